// Round 16
// baseline (289.922 us; speedup 1.0000x reference)
//
#include <hip/hip_runtime.h>
#include <hip/hip_bf16.h>

typedef __attribute__((ext_vector_type(8))) __bf16 bf16x8;
typedef __attribute__((ext_vector_type(4))) float f32x4;
typedef unsigned short u16;
typedef unsigned int u32;
typedef unsigned long long u64;

// ---------- helpers ----------
__device__ __forceinline__ u32 cvtpk(float lo, float hi) {  // {bf16(lo) | bf16(hi)<<16}
  u32 r;
  asm("v_cvt_pk_bf16_f32 %0, %1, %2" : "=v"(r) : "v"(lo), "v"(hi));
  return r;
}
__device__ __forceinline__ float rexp2(float x) {           // raw v_exp_f32 (2^x)
  float r;
  asm("v_exp_f32 %0, %1" : "=v"(r) : "v"(x));
  return r;
}
__device__ __forceinline__ void gl_lds16(const void* g, void* l) {
  __builtin_amdgcn_global_load_lds((const __attribute__((address_space(1))) void*)g,
                                   (__attribute__((address_space(3))) void*)l, 16, 0, 0);
}

// ---------- kernel P: fused prep (xcvt | wcvt | maskbits) ----------
__global__ __launch_bounds__(256) void prep_kernel(
    const float* __restrict__ x, u16* __restrict__ xb,
    const float* __restrict__ Wa, const float* __restrict__ Wp,
    const float* __restrict__ Wk, const float* __restrict__ Wo,
    u16* __restrict__ Wab, u16* __restrict__ Wpb,
    u16* __restrict__ Wkb, u16* __restrict__ Wob,
    const int* __restrict__ mask, u64* __restrict__ bits, int xblocks) {
  int bid = blockIdx.x;
  if (bid < xblocks) {                       // ---- xcvt ----
    const int idx = (bid * 256 + threadIdx.x) * 16;
    const float4 a0 = *(const float4*)(x + idx);
    const float4 a1 = *(const float4*)(x + idx + 4);
    const float4 a2 = *(const float4*)(x + idx + 8);
    const float4 a3 = *(const float4*)(x + idx + 12);
    uint4 t0, t1;
    t0.x = cvtpk(a0.x, a0.y); t0.y = cvtpk(a0.z, a0.w);
    t0.z = cvtpk(a1.x, a1.y); t0.w = cvtpk(a1.z, a1.w);
    t1.x = cvtpk(a2.x, a2.y); t1.y = cvtpk(a2.z, a2.w);
    t1.z = cvtpk(a3.x, a3.y); t1.w = cvtpk(a3.z, a3.w);
    *(uint4*)(xb + idx) = t0;
    *(uint4*)(xb + idx + 8) = t1;
    return;
  }
  bid -= xblocks;
  if (bid < 2560) {                          // ---- wcvt ----
    const float* s; u16* d; int base;
    if (bid < 1536)      { s = Wa; d = Wab; base = bid; }
    else if (bid < 1920) { s = Wp; d = Wpb; base = bid - 1536; }
    else if (bid < 2304) { s = Wk; d = Wkb; base = bid - 1920; }
    else                 { s = Wo; d = Wob; base = bid - 2304; }
    const int idx = (base * 256 + threadIdx.x) * 4;
    const float4 v = *(const float4*)(s + idx);
    *(uint2*)(d + idx) = make_uint2(cvtpk(v.x, v.y), cvtpk(v.z, v.w));
    return;
  }
  bid -= 2560;                               // ---- maskbits ----
  const int lane = threadIdx.x & 63;
  const long long gw = (long long)bid * 4 + (threadIdx.x >> 6);
  const long long nwaves = 1024LL * 4;
  const long long nwords = 16777216LL / 64;
  for (long long i = gw; i < nwords; i += nwaves) {
    const int m = mask[i * 64 + lane];
    const u64 bal = __ballot(m > 0);
    if (lane == 0) bits[i] = bal;
  }
}

// ---------- QKV epilogue store ----------
// Q,K: [B,H,N,64] bf16, segments a@0(32), p@32(16), k@48(16).
// Q PRE-SCALED by (branch D)^-0.5 * log2(e).
// Vt: [bh][d 0..63][n] with n sigma-permuted within each 64-block.
__device__ __forceinline__ void qkv_store(
    float v0, float v1, float v2, float v3, int m_base, int c,
    int dhs, int seg, float fs,
    u16* __restrict__ Qb, u16* __restrict__ Kb, u16* __restrict__ Vt) {
  const int which = c >> (3 + dhs);
  const float f = (which == 0) ? fs : 1.0f;
  const u32 r01 = cvtpk(v0 * f, v1 * f);
  const u32 r23 = cvtpk(v2 * f, v3 * f);
  const u16 bvv[4] = {(u16)r01, (u16)(r01 >> 16), (u16)r23, (u16)(r23 >> 16)};
  const int hd_mask = (8 << dhs) - 1;
  const int r = c & hd_mask;
  const int hh = r >> dhs;
  const int d = r & ((1 << dhs) - 1);
  #pragma unroll
  for (int j = 0; j < 4; ++j) {
    const int m = m_base + j;
    const int bb = m >> 11, n = m & 2047;
    const size_t bhn = (size_t)(bb * 8 + hh) * 2048 + n;
    const u16 bv = bvv[j];
    if (which == 0)      Qb[bhn * 64 + seg + d] = bv;
    else if (which == 1) Kb[bhn * 64 + seg + d] = bv;
    else {
      const int nk6 = n & 63;
      const int pos = ((nk6 >> 5) << 5) | (((nk6 & 15) >> 2) << 3)
                    | ((nk6 & 3) << 1) | ((nk6 >> 4) & 1);
      Vt[((size_t)(bb * 8 + hh) * 64 + seg + d) * 2048 + (n & ~63) + pos] = bv;
    }
  }
}

// ---------- kernel 1a: QKV GEMM bf16, M64xN128 tiles ----------
__global__ __launch_bounds__(256) void qkv_gemm_kernel(
    const u16* __restrict__ xb, const u16* __restrict__ Wa,
    const u16* __restrict__ Wp, const u16* __restrict__ Wk,
    u16* __restrict__ Qb, u16* __restrict__ Kb, u16* __restrict__ Vt) {
  __shared__ u16 lA[64 * 64];
  __shared__ u16 lB[128 * 64];

  const int tid = threadIdx.x;
  const int w = tid >> 6, l = tid & 63;
  const int lr = l & 15, lg = l >> 4;

  const int wg = blockIdx.x;
  const int xcd = wg & 7;
  const int q = wg >> 3;
  const int mtl = q / 12, nt = q % 12;
  const int mt = (xcd << 4) + mtl;

  const u16* W; int xoff, Kd, col0, dhs, seg;
  if (nt < 6)      { W = Wa; xoff = 0;    Kd = 2048; col0 = nt * 128;       dhs = 5; seg = 0;  }
  else if (nt < 9) { W = Wp; xoff = 2048; Kd = 1024; col0 = (nt - 6) * 128; dhs = 4; seg = 32; }
  else             { W = Wk; xoff = 3072; Kd = 1024; col0 = (nt - 9) * 128; dhs = 4; seg = 48; }
  const float qscale = (dhs == 5) ? 0.031880107f : 0.045084220f;  // D^-0.5 * log2(e)

  const int m0 = mt * 64;
  f32x4 acc[4][2] = {};
  const int ubase = tid & ~63;

  const int nk = Kd >> 6;
  #pragma unroll 1
  for (int kt = 0; kt < nk; ++kt) {
    const int k0 = kt << 6;
    #pragma unroll
    for (int i = 0; i < 2; ++i) {
      const int ch = i * 256 + tid;
      const int row = ch >> 3, c8 = (ch & 7) << 3;
      gl_lds16(xb + (size_t)(m0 + row) * 4096 + xoff + k0 + c8,
               lA + (size_t)(i * 256 + ubase) * 8);
    }
    #pragma unroll
    for (int i = 0; i < 4; ++i) {
      const int ch = i * 256 + tid;
      const int row = ch >> 3, c8 = (ch & 7) << 3;
      gl_lds16(W + (size_t)(col0 + row) * Kd + k0 + c8,
               lB + (size_t)(i * 256 + ubase) * 8);
    }
    __syncthreads();
    bf16x8 af[4][2], bfr[2][2];
    #pragma unroll
    for (int mi = 0; mi < 4; ++mi) {
      af[mi][0] = *(const bf16x8*)(lA + (mi * 16 + lr) * 64 + lg * 8);
      af[mi][1] = *(const bf16x8*)(lA + (mi * 16 + lr) * 64 + 32 + lg * 8);
    }
    #pragma unroll
    for (int ni = 0; ni < 2; ++ni) {
      bfr[ni][0] = *(const bf16x8*)(lB + (w * 32 + ni * 16 + lr) * 64 + lg * 8);
      bfr[ni][1] = *(const bf16x8*)(lB + (w * 32 + ni * 16 + lr) * 64 + 32 + lg * 8);
    }
    #pragma unroll
    for (int mi = 0; mi < 4; ++mi)
      #pragma unroll
      for (int ni = 0; ni < 2; ++ni) {
        acc[mi][ni] = __builtin_amdgcn_mfma_f32_16x16x32_bf16(af[mi][0], bfr[ni][0], acc[mi][ni], 0, 0, 0);
        acc[mi][ni] = __builtin_amdgcn_mfma_f32_16x16x32_bf16(af[mi][1], bfr[ni][1], acc[mi][ni], 0, 0, 0);
      }
    __syncthreads();
  }

  #pragma unroll
  for (int mi = 0; mi < 4; ++mi)
    #pragma unroll
    for (int ni = 0; ni < 2; ++ni)
      qkv_store(acc[mi][ni][0], acc[mi][ni][1], acc[mi][ni][2], acc[mi][ni][3],
                m0 + mi * 16 + lg * 4, col0 + w * 32 + ni * 16 + lr,
                dhs, seg, qscale, Qb, Kb, Vt);
}

// ---------- kernel 1b: fallback, x fp32 reg-staged (if ws too small) ----------
__global__ __launch_bounds__(256) void qkv_gemm_f32_kernel(
    const float* __restrict__ x, const u16* __restrict__ Wa,
    const u16* __restrict__ Wp, const u16* __restrict__ Wk,
    u16* __restrict__ Qb, u16* __restrict__ Kb, u16* __restrict__ Vt) {
  __shared__ u16 lA[128 * 64];
  __shared__ u16 lB[128 * 64];

  const int tid = threadIdx.x;
  const int w = tid >> 6, l = tid & 63;
  const int lr = l & 15, lg = l >> 4;
  const int wr = w >> 1, wc = w & 1;

  const int wg = blockIdx.x;
  const int xcd = wg & 7;
  const int q = wg >> 3;
  const int mtl = q / 12, nt = q % 12;
  const int mt = (xcd << 3) + mtl;

  const u16* W; int xoff, Kd, col0, dhs, seg;
  if (nt < 6)      { W = Wa; xoff = 0;    Kd = 2048; col0 = nt * 128;       dhs = 5; seg = 0;  }
  else if (nt < 9) { W = Wp; xoff = 2048; Kd = 1024; col0 = (nt - 6) * 128; dhs = 4; seg = 32; }
  else             { W = Wk; xoff = 3072; Kd = 1024; col0 = (nt - 9) * 128; dhs = 4; seg = 48; }
  const float qscale = (dhs == 5) ? 0.031880107f : 0.045084220f;

  const int m0 = mt * 128;
  f32x4 acc[4][4] = {};
  const int ubase = tid & ~63;

  const int nk = Kd >> 6;
  #pragma unroll 1
  for (int kt = 0; kt < nk; ++kt) {
    const int k0 = kt << 6;
    #pragma unroll
    for (int i = 0; i < 4; ++i) {
      const int ch = i * 256 + tid;
      const int row = ch >> 3, c8 = (ch & 7) << 3;
      const float* src = x + (size_t)(m0 + row) * 4096 + xoff + k0 + c8;
      const float4 a0 = *(const float4*)(src);
      const float4 a1 = *(const float4*)(src + 4);
      uint4 t;
      t.x = cvtpk(a0.x, a0.y); t.y = cvtpk(a0.z, a0.w);
      t.z = cvtpk(a1.x, a1.y); t.w = cvtpk(a1.z, a1.w);
      *(uint4*)(lA + (size_t)row * 64 + c8) = t;
    }
    #pragma unroll
    for (int i = 0; i < 4; ++i) {
      const int ch = i * 256 + tid;
      const int row = ch >> 3, c8 = (ch & 7) << 3;
      gl_lds16(W + (size_t)(col0 + row) * Kd + k0 + c8,
               lB + (size_t)(i * 256 + ubase) * 8);
    }
    __syncthreads();
    bf16x8 af[4][2], bfr[4][2];
    #pragma unroll
    for (int mi = 0; mi < 4; ++mi) {
      af[mi][0] = *(const bf16x8*)(lA + (wr * 64 + mi * 16 + lr) * 64 + lg * 8);
      af[mi][1] = *(const bf16x8*)(lA + (wr * 64 + mi * 16 + lr) * 64 + 32 + lg * 8);
    }
    #pragma unroll
    for (int ni = 0; ni < 4; ++ni) {
      bfr[ni][0] = *(const bf16x8*)(lB + (wc * 64 + ni * 16 + lr) * 64 + lg * 8);
      bfr[ni][1] = *(const bf16x8*)(lB + (wc * 64 + ni * 16 + lr) * 64 + 32 + lg * 8);
    }
    #pragma unroll
    for (int mi = 0; mi < 4; ++mi)
      #pragma unroll
      for (int ni = 0; ni < 4; ++ni) {
        acc[mi][ni] = __builtin_amdgcn_mfma_f32_16x16x32_bf16(af[mi][0], bfr[ni][0], acc[mi][ni], 0, 0, 0);
        acc[mi][ni] = __builtin_amdgcn_mfma_f32_16x16x32_bf16(af[mi][1], bfr[ni][1], acc[mi][ni], 0, 0, 0);
      }
    __syncthreads();
  }
  #pragma unroll
  for (int mi = 0; mi < 4; ++mi)
    #pragma unroll
    for (int ni = 0; ni < 4; ++ni)
      qkv_store(acc[mi][ni][0], acc[mi][ni][1], acc[mi][ni][2], acc[mi][ni][3],
                m0 + wr * 64 + mi * 16 + lg * 4, col0 + wc * 64 + ni * 16 + lr,
                dhs, seg, qscale, Qb, Kb, Vt);
}

// ---------- kernel 2: fused 3-branch flash attention ----------
// QBLK=128 (512 thr). Counted vmcnt(2) dbuf + 2x unroll (unchanged sync template).
// NEW: segment-skewed pipeline — QK(a),QK(p) issued up front; QK(k) reuses kfB
// registers (p and k read the SAME K chunks); each softpv overlaps the next QK.
__global__ __launch_bounds__(512) void attn_kernel(
    const u16* __restrict__ Qb, const u16* __restrict__ Kb,
    const u16* __restrict__ Vt, const u32* __restrict__ mbits,
    u16* __restrict__ aout) {
  struct SMem {
    u16 sK[2][64 * 64];   // 2 x 8192 B
    u16 sV[2][64 * 64];   // 2 x 8192 B
  };
  __shared__ SMem sm;     // 32768 B

  const int tid = threadIdx.x;
  const int w = tid >> 6, l = tid & 63;
  const int lr = l & 15, lg = l >> 4;
  const int wg = blockIdx.x;            // 0..511
  const int xcd = wg & 7, rr0 = wg >> 3;
  const int bh = (xcd << 2) + (rr0 >> 4);   // each XCD: 4 bh x 16 qt
  const int qt = rr0 & 15;
  const int b = bh >> 3, h = bh & 7;
  const int q0 = qt << 7;               // 128 q-rows per block
  const size_t bhN = (size_t)bh * 2048;
  const int ubase = tid & ~63;

  // Q fragments: a (full 32) + pk split into zero-half p/k variants (k=lg*8+e).
  const u16* qrow = Qb + (bhN + q0 + w * 16 + lr) * 64;
  const bf16x8 qf_a  = *(const bf16x8*)(qrow + lg * 8);
  const bf16x8 qf_pk = *(const bf16x8*)(qrow + 32 + lg * 8);
  bf16x8 zero8 = {};
  const bf16x8 qf_p = (lg < 2) ? qf_pk : zero8;
  const bf16x8 qf_k = (lg < 2) ? zero8 : qf_pk;

  const u32* mptr = mbits + ((size_t)b * 2048 + q0 + w * 16 + lr) * 64;

  // per-thread staging sources (1 chunk each for K and V; chunk wd of row r at wd^(r&7))
  const int sr = tid >> 3, swd = tid & 7;
  const u16* kp = Kb + (bhN + sr) * 64 + (swd ^ (sr & 7)) * 8;          // + kt*4096
  const u16* vp = Vt + ((size_t)bh * 64 + sr) * 2048 + (swd ^ (sr & 7)) * 8;  // + kt*64
  u16* dK[2] = { &sm.sK[0][0] + ubase * 8, &sm.sK[1][0] + ubase * 8 };
  u16* dV[2] = { &sm.sV[0][0] + ubase * 8, &sm.sV[1][0] + ubase * 8 };

  // prologue: stage tile 0 into buf 0 (2 loads in flight per wave)
  gl_lds16(kp, dK[0]);
  gl_lds16(vp, dV[0]);

  bf16x8 vones;
  #pragma unroll
  for (int e = 0; e < 8; ++e) vones[e] = __builtin_bit_cast(__bf16, (u16)0x3F80);

  f32x4 oacc[3][4] = {};
  f32x4 osum[3] = {};
  const int c4 = (lg << 2);
  const int xk = lr & 7;

  auto body = [&](int kt, int cur, bool st) {
    // issue next tile's 2 loads first (stay in flight across the barrier)
    if (st) {
      gl_lds16(kp + (size_t)(kt + 1) * 4096, dK[cur ^ 1]);
      gl_lds16(vp + (size_t)(kt + 1) * 64, dV[cur ^ 1]);
      asm volatile("s_waitcnt vmcnt(2)" ::: "memory");  // own-wave cur-tile loads done
    } else {
      asm volatile("s_waitcnt vmcnt(0)" ::: "memory");
    }
    __builtin_amdgcn_sched_barrier(0);
    __builtin_amdgcn_s_barrier();   // B1: all waves' cur-tile data landed

    const uint2 mk = *(const uint2*)(mptr + (kt << 1));
    u32 msk[4][2];
    #pragma unroll
    for (int j = 0; j < 4; ++j) {
      const int c = c4 + j;
      const u32 u0 = (mk.x >> c) & 0x00010001u;
      const u32 u1 = (mk.y >> c) & 0x00010001u;
      msk[j][0] = (u0 << 16) - u0;
      msk[j][1] = (u1 << 16) - u1;
    }

    bf16x8 vb[4][2];
    #pragma unroll
    for (int ct = 0; ct < 4; ++ct) {
      const u16* vrow = &sm.sV[cur][0] + (ct * 16 + lr) * 64;
      vb[ct][0] = *(const bf16x8*)(vrow + (lg ^ xk) * 8);
      vb[ct][1] = *(const bf16x8*)(vrow + ((lg + 4) ^ xk) * 8);
    }

    const f32x4 fz = {0.f, 0.f, 0.f, 0.f};
    auto softpv = [&](f32x4 (&sacc)[4], int s) {
      uint4 pw0, pw1;
      u32* w0 = (u32*)&pw0; u32* w1 = (u32*)&pw1;
      #pragma unroll
      for (int j = 0; j < 4; ++j) {
        w0[j] = cvtpk(rexp2(sacc[0][j]), rexp2(sacc[1][j])) & msk[j][0];
        w1[j] = cvtpk(rexp2(sacc[2][j]), rexp2(sacc[3][j])) & msk[j][1];
      }
      const bf16x8 pa0 = __builtin_bit_cast(bf16x8, pw0);
      const bf16x8 pa1 = __builtin_bit_cast(bf16x8, pw1);
      __builtin_amdgcn_s_setprio(1);
      #pragma unroll
      for (int ct = 0; ct < 4; ++ct) {
        oacc[s][ct] = __builtin_amdgcn_mfma_f32_16x16x32_bf16(pa0, vb[ct][0], oacc[s][ct], 0, 0, 0);
        oacc[s][ct] = __builtin_amdgcn_mfma_f32_16x16x32_bf16(pa1, vb[ct][1], oacc[s][ct], 0, 0, 0);
      }
      osum[s] = __builtin_amdgcn_mfma_f32_16x16x32_bf16(pa0, vones, osum[s], 0, 0, 0);
      osum[s] = __builtin_amdgcn_mfma_f32_16x16x32_bf16(pa1, vones, osum[s], 0, 0, 0);
      __builtin_amdgcn_s_setprio(0);
    };

    // --- skewed pipeline: QK(a) + QK(p) first; QK(k) reuses kfB registers ---
    f32x4 sA[4], sB[4], sC[4];
    bf16x8 kfB[4];
    {
      __builtin_amdgcn_s_setprio(1);
      #pragma unroll
      for (int t = 0; t < 4; ++t) {           // QK seg a (chunks 0-3)
        const bf16x8 kf = *(const bf16x8*)(&sm.sK[cur][0] + (t * 16 + lr) * 64 + ((lg ^ xk) * 8));
        sA[t] = __builtin_amdgcn_mfma_f32_16x16x32_bf16(kf, qf_a, fz, 0, 0, 0);
      }
      #pragma unroll
      for (int t = 0; t < 4; ++t) {           // QK seg p (chunks 4-7)
        kfB[t] = *(const bf16x8*)(&sm.sK[cur][0] + (t * 16 + lr) * 64 + (((lg + 4) ^ xk) * 8));
        sB[t] = __builtin_amdgcn_mfma_f32_16x16x32_bf16(kfB[t], qf_p, fz, 0, 0, 0);
      }
      __builtin_amdgcn_s_setprio(0);
    }
    softpv(sA, 0);                            // overlaps with QK issue above
    {
      __builtin_amdgcn_s_setprio(1);
      #pragma unroll
      for (int t = 0; t < 4; ++t)             // QK seg k — kfB reuse, no LDS reads
        sC[t] = __builtin_amdgcn_mfma_f32_16x16x32_bf16(kfB[t], qf_k, fz, 0, 0, 0);
      __builtin_amdgcn_s_setprio(0);
    }
    softpv(sB, 1);
    softpv(sC, 2);

    __builtin_amdgcn_s_barrier();   // B2: all waves done reading buf[cur]
  };

  #pragma unroll 1
  for (int it = 0; it < 16; ++it) {
    body(2 * it, 0, true);
    body(2 * it + 1, 1, it < 15);
  }

  float linv[3][4];
  #pragma unroll
  for (int s = 0; s < 3; ++s)
    #pragma unroll
    for (int j = 0; j < 4; ++j)
      linv[s][j] = 1.0f / (3.0f * osum[s][j] + 1e-30f);

  #pragma unroll
  for (int ct = 0; ct < 4; ++ct) {
    float vj[4];
    #pragma unroll
    for (int j = 0; j < 4; ++j)
      vj[j] = oacc[0][ct][j] * linv[0][j]
            + oacc[1][ct][j] * linv[1][j]
            + oacc[2][ct][j] * linv[2][j];
    const u32 r01 = cvtpk(vj[0], vj[1]);
    const u32 r23 = cvtpk(vj[2], vj[3]);
    const u16 bvv[4] = {(u16)r01, (u16)(r01 >> 16), (u16)r23, (u16)(r23 >> 16)};
    #pragma unroll
    for (int j = 0; j < 4; ++j) {
      const int row = q0 + w * 16 + lg * 4 + j;
      const int col = h * 64 + ct * 16 + lr;
      aout[((size_t)b * 2048 + row) * 512 + col] = bvv[j];
    }
  }
}

// ---------- kernel 3: output projection, M64xN64 tiles ----------
__global__ __launch_bounds__(256) void out_gemm_kernel(
    const u16* __restrict__ A, const u16* __restrict__ Wo,
    const float* __restrict__ bias, float* __restrict__ out) {
  __shared__ u16 lA[64 * 64];
  __shared__ u16 lB[64 * 64];

  const int tid = threadIdx.x;
  const int w = tid >> 6, l = tid & 63;
  const int lr = l & 15, lg = l >> 4;

  const int wg = blockIdx.x;
  const int xcd = wg & 7;
  const int q = wg >> 3;
  const int mt = (xcd << 4) + (q >> 3);
  const int nt = q & 7;
  const int col0 = nt * 64;
  const int m0 = mt * 64;
  f32x4 acc[4] = {};
  const int ubase = tid & ~63;

  #pragma unroll 1
  for (int kt = 0; kt < 8; ++kt) {
    const int k0 = kt << 6;
    #pragma unroll
    for (int i = 0; i < 2; ++i) {
      const int ch = i * 256 + tid;
      const int row = ch >> 3, c8 = (ch & 7) << 3;
      gl_lds16(A + (size_t)(m0 + row) * 512 + k0 + c8, lA + (size_t)(i * 256 + ubase) * 8);
    }
    #pragma unroll
    for (int i = 0; i < 2; ++i) {
      const int ch = i * 256 + tid;
      const int row = ch >> 3, c8 = (ch & 7) << 3;
      gl_lds16(Wo + (size_t)(col0 + row) * 512 + k0 + c8, lB + (size_t)(i * 256 + ubase) * 8);
    }
    __syncthreads();
    bf16x8 af[4][2], bfr[2];
    #pragma unroll
    for (int mi = 0; mi < 4; ++mi) {
      af[mi][0] = *(const bf16x8*)(lA + (mi * 16 + lr) * 64 + lg * 8);
      af[mi][1] = *(const bf16x8*)(lA + (mi * 16 + lr) * 64 + 32 + lg * 8);
    }
    bfr[0] = *(const bf16x8*)(lB + (w * 16 + lr) * 64 + lg * 8);
    bfr[1] = *(const bf16x8*)(lB + (w * 16 + lr) * 64 + 32 + lg * 8);
    #pragma unroll
    for (int mi = 0; mi < 4; ++mi) {
      acc[mi] = __builtin_amdgcn_mfma_f32_16x16x32_bf16(af[mi][0], bfr[0], acc[mi], 0, 0, 0);
      acc[mi] = __builtin_amdgcn_mfma_f32_16x16x32_bf16(af[mi][1], bfr[1], acc[mi], 0, 0, 0);
    }
    __syncthreads();
  }

  const int c = col0 + w * 16 + lr;
  const float bv = bias[c];
  #pragma unroll
  for (int mi = 0; mi < 4; ++mi)
    #pragma unroll
    for (int j = 0; j < 4; ++j) {
      const int m = m0 + mi * 16 + lg * 4 + j;
      out[(size_t)m * 512 + c] = acc[mi][j] + bv;
    }
}

// ---------- launcher ----------
extern "C" void kernel_launch(void* const* d_in, const int* in_sizes, int n_in,
                              void* d_out, int out_size, void* d_ws, size_t ws_size,
                              hipStream_t stream) {
  const float* x    = (const float*)d_in[0];
  const float* Wa   = (const float*)d_in[1];
  const float* Wp   = (const float*)d_in[2];
  const float* Wk   = (const float*)d_in[3];
  const float* Wo   = (const float*)d_in[4];
  const float* bo   = (const float*)d_in[5];
  const int* mask   = (const int*)d_in[6];
  float* out = (float*)d_out;

  char* ws = (char*)d_ws;
  u16* Wab = (u16*)ws;                    //  3,145,728 B
  u16* Wpb = (u16*)(ws + 3145728);        //    786,432 B
  u16* Wkb = (u16*)(ws + 3932160);        //    786,432 B
  u16* Wob = (u16*)(ws + 4718592);        //    524,288 B
  u16* Qb  = (u16*)(ws + 5242880);        //  8,388,608 B  [B,H,N,64] bf16
  u16* Kb  = (u16*)(ws + 13631488);       //  8,388,608 B  [B,H,N,64] bf16
  u16* Vt  = (u16*)(ws + 22020096);       //  8,388,608 B  [B*H,64,2048] bf16 (sigma-perm)
  u64* Mb  = (u64*)(ws + 30408704);       //  2,097,152 B  bitmask
  u16* Ao  = (u16*)(ws + 32505856);       //  8,388,608 B  [B,N,512] bf16
  u16* xb  = (u16*)(ws + 40894464);       // 67,108,864 B  x bf16 (optional)

  const bool use_xb = ws_size >= (size_t)40894464 + 67108864;
  const int xblocks = use_xb ? 8192 : 0;

  prep_kernel<<<xblocks + 2560 + 1024, 256, 0, stream>>>(
      x, xb, Wa, Wp, Wk, Wo, Wab, Wpb, Wkb, Wob, mask, (u64*)Mb, xblocks);
  if (use_xb) {
    qkv_gemm_kernel<<<1536, 256, 0, stream>>>(xb, Wab, Wpb, Wkb, Qb, Kb, Vt);
  } else {
    qkv_gemm_f32_kernel<<<768, 256, 0, stream>>>(x, Wab, Wpb, Wkb, Qb, Kb, Vt);
  }
  attn_kernel<<<512, 512, 0, stream>>>(Qb, Kb, Vt, (const u32*)Mb, Ao);
  out_gemm_kernel<<<1024, 256, 0, stream>>>(Ao, Wob, bo, out);
}

// Round 17
// 278.199 us; speedup vs baseline: 1.0421x; 1.0421x over previous
//
#include <hip/hip_runtime.h>
#include <hip/hip_bf16.h>

typedef __attribute__((ext_vector_type(8))) __bf16 bf16x8;
typedef __attribute__((ext_vector_type(4))) float f32x4;
typedef unsigned short u16;
typedef unsigned int u32;
typedef unsigned long long u64;

// ---------- helpers ----------
__device__ __forceinline__ u32 cvtpk(float lo, float hi) {  // {bf16(lo) | bf16(hi)<<16}
  u32 r;
  asm("v_cvt_pk_bf16_f32 %0, %1, %2" : "=v"(r) : "v"(lo), "v"(hi));
  return r;
}
__device__ __forceinline__ float rexp2(float x) {           // raw v_exp_f32 (2^x)
  float r;
  asm("v_exp_f32 %0, %1" : "=v"(r) : "v"(x));
  return r;
}
__device__ __forceinline__ void gl_lds16(const void* g, void* l) {
  __builtin_amdgcn_global_load_lds((const __attribute__((address_space(1))) void*)g,
                                   (__attribute__((address_space(3))) void*)l, 16, 0, 0);
}

// ---------- kernel P: fused prep (xcvt | wcvt | maskbits) ----------
__global__ __launch_bounds__(256) void prep_kernel(
    const float* __restrict__ x, u16* __restrict__ xb,
    const float* __restrict__ Wa, const float* __restrict__ Wp,
    const float* __restrict__ Wk, const float* __restrict__ Wo,
    u16* __restrict__ Wab, u16* __restrict__ Wpb,
    u16* __restrict__ Wkb, u16* __restrict__ Wob,
    const int* __restrict__ mask, u64* __restrict__ bits, int xblocks) {
  int bid = blockIdx.x;
  if (bid < xblocks) {                       // ---- xcvt ----
    const int idx = (bid * 256 + threadIdx.x) * 16;
    const float4 a0 = *(const float4*)(x + idx);
    const float4 a1 = *(const float4*)(x + idx + 4);
    const float4 a2 = *(const float4*)(x + idx + 8);
    const float4 a3 = *(const float4*)(x + idx + 12);
    uint4 t0, t1;
    t0.x = cvtpk(a0.x, a0.y); t0.y = cvtpk(a0.z, a0.w);
    t0.z = cvtpk(a1.x, a1.y); t0.w = cvtpk(a1.z, a1.w);
    t1.x = cvtpk(a2.x, a2.y); t1.y = cvtpk(a2.z, a2.w);
    t1.z = cvtpk(a3.x, a3.y); t1.w = cvtpk(a3.z, a3.w);
    *(uint4*)(xb + idx) = t0;
    *(uint4*)(xb + idx + 8) = t1;
    return;
  }
  bid -= xblocks;
  if (bid < 2560) {                          // ---- wcvt ----
    const float* s; u16* d; int base;
    if (bid < 1536)      { s = Wa; d = Wab; base = bid; }
    else if (bid < 1920) { s = Wp; d = Wpb; base = bid - 1536; }
    else if (bid < 2304) { s = Wk; d = Wkb; base = bid - 1920; }
    else                 { s = Wo; d = Wob; base = bid - 2304; }
    const int idx = (base * 256 + threadIdx.x) * 4;
    const float4 v = *(const float4*)(s + idx);
    *(uint2*)(d + idx) = make_uint2(cvtpk(v.x, v.y), cvtpk(v.z, v.w));
    return;
  }
  bid -= 2560;                               // ---- maskbits ----
  const int lane = threadIdx.x & 63;
  const long long gw = (long long)bid * 4 + (threadIdx.x >> 6);
  const long long nwaves = 1024LL * 4;
  const long long nwords = 16777216LL / 64;
  for (long long i = gw; i < nwords; i += nwaves) {
    const int m = mask[i * 64 + lane];
    const u64 bal = __ballot(m > 0);
    if (lane == 0) bits[i] = bal;
  }
}

// ---------- QKV epilogue store ----------
// Q,K: [B,H,N,64] bf16, segments a@0(32), p@32(16), k@48(16).
// Q PRE-SCALED by (branch D)^-0.5 * log2(e).
// V: n-major [bh][n][64] (coalesced store; transposed to Vt by vtr_kernel).
__device__ __forceinline__ void qkv_store(
    float v0, float v1, float v2, float v3, int m_base, int c,
    int dhs, int seg, float fs,
    u16* __restrict__ Qb, u16* __restrict__ Kb, u16* __restrict__ Vb) {
  const int which = c >> (3 + dhs);
  const float f = (which == 0) ? fs : 1.0f;
  const u32 r01 = cvtpk(v0 * f, v1 * f);
  const u32 r23 = cvtpk(v2 * f, v3 * f);
  const u16 bvv[4] = {(u16)r01, (u16)(r01 >> 16), (u16)r23, (u16)(r23 >> 16)};
  const int hd_mask = (8 << dhs) - 1;
  const int r = c & hd_mask;
  const int hh = r >> dhs;
  const int d = r & ((1 << dhs) - 1);
  #pragma unroll
  for (int j = 0; j < 4; ++j) {
    const int m = m_base + j;
    const int bb = m >> 11, n = m & 2047;
    const size_t bhn = (size_t)(bb * 8 + hh) * 2048 + n;
    const u16 bv = bvv[j];
    if (which == 0)      Qb[bhn * 64 + seg + d] = bv;
    else if (which == 1) Kb[bhn * 64 + seg + d] = bv;
    else                 Vb[bhn * 64 + seg + d] = bv;
  }
}

// ---------- kernel V: V n-major -> Vt d-major with sigma perm (LDS transpose) ----------
// grid 1024 = bh(32) x nblk(32); tile [64 n][64 d]; sigma applied at LDS write so
// both global read and write are fully coalesced uint4.
__global__ __launch_bounds__(256) void vtr_kernel(const u16* __restrict__ Vb,
                                                  u16* __restrict__ Vt) {
  __shared__ u16 lt[64 * 72];
  const int tid = threadIdx.x;
  const int bh = blockIdx.x >> 5;
  const int n0 = (blockIdx.x & 31) << 6;
  #pragma unroll
  for (int i = 0; i < 2; ++i) {
    const int idx = (i * 256 + tid) * 8;
    const int n = idx >> 6, d0 = idx & 63;
    union { uint4 v; u16 h[8]; } t;
    t.v = *(const uint4*)(Vb + ((size_t)bh * 2048 + n0 + n) * 64 + d0);
    const int pos = ((n >> 5) << 5) | (((n & 15) >> 2) << 3)
                  | ((n & 3) << 1) | ((n >> 4) & 1);     // sigma^-1(n)
    #pragma unroll
    for (int e = 0; e < 8; ++e) lt[(d0 + e) * 72 + pos] = t.h[e];
  }
  __syncthreads();
  #pragma unroll
  for (int i = 0; i < 2; ++i) {
    const int idx = (i * 256 + tid) * 8;
    const int d = idx >> 6, p0 = idx & 63;
    *(uint4*)(Vt + ((size_t)bh * 64 + d) * 2048 + n0 + p0) =
        *(const uint4*)(lt + d * 72 + p0);
  }
}

// ---------- kernel 1a: QKV GEMM bf16, M64xN128 tiles ----------
__global__ __launch_bounds__(256) void qkv_gemm_kernel(
    const u16* __restrict__ xb, const u16* __restrict__ Wa,
    const u16* __restrict__ Wp, const u16* __restrict__ Wk,
    u16* __restrict__ Qb, u16* __restrict__ Kb, u16* __restrict__ Vb) {
  __shared__ u16 lA[64 * 64];
  __shared__ u16 lB[128 * 64];

  const int tid = threadIdx.x;
  const int w = tid >> 6, l = tid & 63;
  const int lr = l & 15, lg = l >> 4;

  const int wg = blockIdx.x;
  const int xcd = wg & 7;
  const int q = wg >> 3;
  const int mtl = q / 12, nt = q % 12;
  const int mt = (xcd << 4) + mtl;

  const u16* W; int xoff, Kd, col0, dhs, seg;
  if (nt < 6)      { W = Wa; xoff = 0;    Kd = 2048; col0 = nt * 128;       dhs = 5; seg = 0;  }
  else if (nt < 9) { W = Wp; xoff = 2048; Kd = 1024; col0 = (nt - 6) * 128; dhs = 4; seg = 32; }
  else             { W = Wk; xoff = 3072; Kd = 1024; col0 = (nt - 9) * 128; dhs = 4; seg = 48; }
  const float qscale = (dhs == 5) ? 0.031880107f : 0.045084220f;  // D^-0.5 * log2(e)

  const int m0 = mt * 64;
  f32x4 acc[4][2] = {};
  const int ubase = tid & ~63;

  const int nk = Kd >> 6;
  #pragma unroll 1
  for (int kt = 0; kt < nk; ++kt) {
    const int k0 = kt << 6;
    #pragma unroll
    for (int i = 0; i < 2; ++i) {
      const int ch = i * 256 + tid;
      const int row = ch >> 3, c8 = (ch & 7) << 3;
      gl_lds16(xb + (size_t)(m0 + row) * 4096 + xoff + k0 + c8,
               lA + (size_t)(i * 256 + ubase) * 8);
    }
    #pragma unroll
    for (int i = 0; i < 4; ++i) {
      const int ch = i * 256 + tid;
      const int row = ch >> 3, c8 = (ch & 7) << 3;
      gl_lds16(W + (size_t)(col0 + row) * Kd + k0 + c8,
               lB + (size_t)(i * 256 + ubase) * 8);
    }
    __syncthreads();
    bf16x8 af[4][2], bfr[2][2];
    #pragma unroll
    for (int mi = 0; mi < 4; ++mi) {
      af[mi][0] = *(const bf16x8*)(lA + (mi * 16 + lr) * 64 + lg * 8);
      af[mi][1] = *(const bf16x8*)(lA + (mi * 16 + lr) * 64 + 32 + lg * 8);
    }
    #pragma unroll
    for (int ni = 0; ni < 2; ++ni) {
      bfr[ni][0] = *(const bf16x8*)(lB + (w * 32 + ni * 16 + lr) * 64 + lg * 8);
      bfr[ni][1] = *(const bf16x8*)(lB + (w * 32 + ni * 16 + lr) * 64 + 32 + lg * 8);
    }
    #pragma unroll
    for (int mi = 0; mi < 4; ++mi)
      #pragma unroll
      for (int ni = 0; ni < 2; ++ni) {
        acc[mi][ni] = __builtin_amdgcn_mfma_f32_16x16x32_bf16(af[mi][0], bfr[ni][0], acc[mi][ni], 0, 0, 0);
        acc[mi][ni] = __builtin_amdgcn_mfma_f32_16x16x32_bf16(af[mi][1], bfr[ni][1], acc[mi][ni], 0, 0, 0);
      }
    __syncthreads();
  }

  #pragma unroll
  for (int mi = 0; mi < 4; ++mi)
    #pragma unroll
    for (int ni = 0; ni < 2; ++ni)
      qkv_store(acc[mi][ni][0], acc[mi][ni][1], acc[mi][ni][2], acc[mi][ni][3],
                m0 + mi * 16 + lg * 4, col0 + w * 32 + ni * 16 + lr,
                dhs, seg, qscale, Qb, Kb, Vb);
}

// ---------- kernel 1b: fallback, x fp32 reg-staged (if ws too small) ----------
__global__ __launch_bounds__(256) void qkv_gemm_f32_kernel(
    const float* __restrict__ x, const u16* __restrict__ Wa,
    const u16* __restrict__ Wp, const u16* __restrict__ Wk,
    u16* __restrict__ Qb, u16* __restrict__ Kb, u16* __restrict__ Vb) {
  __shared__ u16 lA[128 * 64];
  __shared__ u16 lB[128 * 64];

  const int tid = threadIdx.x;
  const int w = tid >> 6, l = tid & 63;
  const int lr = l & 15, lg = l >> 4;
  const int wr = w >> 1, wc = w & 1;

  const int wg = blockIdx.x;
  const int xcd = wg & 7;
  const int q = wg >> 3;
  const int mtl = q / 12, nt = q % 12;
  const int mt = (xcd << 3) + mtl;

  const u16* W; int xoff, Kd, col0, dhs, seg;
  if (nt < 6)      { W = Wa; xoff = 0;    Kd = 2048; col0 = nt * 128;       dhs = 5; seg = 0;  }
  else if (nt < 9) { W = Wp; xoff = 2048; Kd = 1024; col0 = (nt - 6) * 128; dhs = 4; seg = 32; }
  else             { W = Wk; xoff = 3072; Kd = 1024; col0 = (nt - 9) * 128; dhs = 4; seg = 48; }
  const float qscale = (dhs == 5) ? 0.031880107f : 0.045084220f;

  const int m0 = mt * 128;
  f32x4 acc[4][4] = {};
  const int ubase = tid & ~63;

  const int nk = Kd >> 6;
  #pragma unroll 1
  for (int kt = 0; kt < nk; ++kt) {
    const int k0 = kt << 6;
    #pragma unroll
    for (int i = 0; i < 4; ++i) {
      const int ch = i * 256 + tid;
      const int row = ch >> 3, c8 = (ch & 7) << 3;
      const float* src = x + (size_t)(m0 + row) * 4096 + xoff + k0 + c8;
      const float4 a0 = *(const float4*)(src);
      const float4 a1 = *(const float4*)(src + 4);
      uint4 t;
      t.x = cvtpk(a0.x, a0.y); t.y = cvtpk(a0.z, a0.w);
      t.z = cvtpk(a1.x, a1.y); t.w = cvtpk(a1.z, a1.w);
      *(uint4*)(lA + (size_t)row * 64 + c8) = t;
    }
    #pragma unroll
    for (int i = 0; i < 4; ++i) {
      const int ch = i * 256 + tid;
      const int row = ch >> 3, c8 = (ch & 7) << 3;
      gl_lds16(W + (size_t)(col0 + row) * Kd + k0 + c8,
               lB + (size_t)(i * 256 + ubase) * 8);
    }
    __syncthreads();
    bf16x8 af[4][2], bfr[4][2];
    #pragma unroll
    for (int mi = 0; mi < 4; ++mi) {
      af[mi][0] = *(const bf16x8*)(lA + (wr * 64 + mi * 16 + lr) * 64 + lg * 8);
      af[mi][1] = *(const bf16x8*)(lA + (wr * 64 + mi * 16 + lr) * 64 + 32 + lg * 8);
    }
    #pragma unroll
    for (int ni = 0; ni < 4; ++ni) {
      bfr[ni][0] = *(const bf16x8*)(lB + (wc * 64 + ni * 16 + lr) * 64 + lg * 8);
      bfr[ni][1] = *(const bf16x8*)(lB + (wc * 64 + ni * 16 + lr) * 64 + 32 + lg * 8);
    }
    #pragma unroll
    for (int mi = 0; mi < 4; ++mi)
      #pragma unroll
      for (int ni = 0; ni < 4; ++ni) {
        acc[mi][ni] = __builtin_amdgcn_mfma_f32_16x16x32_bf16(af[mi][0], bfr[ni][0], acc[mi][ni], 0, 0, 0);
        acc[mi][ni] = __builtin_amdgcn_mfma_f32_16x16x32_bf16(af[mi][1], bfr[ni][1], acc[mi][ni], 0, 0, 0);
      }
    __syncthreads();
  }
  #pragma unroll
  for (int mi = 0; mi < 4; ++mi)
    #pragma unroll
    for (int ni = 0; ni < 4; ++ni)
      qkv_store(acc[mi][ni][0], acc[mi][ni][1], acc[mi][ni][2], acc[mi][ni][3],
                m0 + wr * 64 + mi * 16 + lg * 4, col0 + wc * 64 + ni * 16 + lr,
                dhs, seg, qscale, Qb, Kb, Vb);
}

// ---------- kernel 2: fused 3-branch flash attention (R14 structure, VGPR 80) ----------
// QBLK=128 (512 thr): 1 K-gl_lds + 1 V-gl_lds per wave per tile.
// Counted vmcnt(2) pipelined dbuf, manual 2x unroll (literal buffer index).
__global__ __launch_bounds__(512) void attn_kernel(
    const u16* __restrict__ Qb, const u16* __restrict__ Kb,
    const u16* __restrict__ Vt, const u32* __restrict__ mbits,
    u16* __restrict__ aout) {
  struct SMem {
    u16 sK[2][64 * 64];   // 2 x 8192 B
    u16 sV[2][64 * 64];   // 2 x 8192 B
  };
  __shared__ SMem sm;     // 32768 B

  const int tid = threadIdx.x;
  const int w = tid >> 6, l = tid & 63;
  const int lr = l & 15, lg = l >> 4;
  const int wg = blockIdx.x;            // 0..511
  const int xcd = wg & 7, rr0 = wg >> 3;
  const int bh = (xcd << 2) + (rr0 >> 4);   // each XCD: 4 bh x 16 qt
  const int qt = rr0 & 15;
  const int b = bh >> 3, h = bh & 7;
  const int q0 = qt << 7;               // 128 q-rows per block
  const size_t bhN = (size_t)bh * 2048;
  const int ubase = tid & ~63;

  // Q fragments: a (full 32) + pk split into zero-half p/k variants (k=lg*8+e).
  const u16* qrow = Qb + (bhN + q0 + w * 16 + lr) * 64;
  const bf16x8 qf_a  = *(const bf16x8*)(qrow + lg * 8);
  const bf16x8 qf_pk = *(const bf16x8*)(qrow + 32 + lg * 8);
  bf16x8 zero8 = {};
  const bf16x8 qf_p = (lg < 2) ? qf_pk : zero8;
  const bf16x8 qf_k = (lg < 2) ? zero8 : qf_pk;

  const u32* mptr = mbits + ((size_t)b * 2048 + q0 + w * 16 + lr) * 64;

  // per-thread staging sources (1 chunk each for K and V; chunk wd of row r at wd^(r&7))
  const int sr = tid >> 3, swd = tid & 7;
  const u16* kp = Kb + (bhN + sr) * 64 + (swd ^ (sr & 7)) * 8;          // + kt*4096
  const u16* vp = Vt + ((size_t)bh * 64 + sr) * 2048 + (swd ^ (sr & 7)) * 8;  // + kt*64
  u16* dK[2] = { &sm.sK[0][0] + ubase * 8, &sm.sK[1][0] + ubase * 8 };
  u16* dV[2] = { &sm.sV[0][0] + ubase * 8, &sm.sV[1][0] + ubase * 8 };

  // prologue: stage tile 0 into buf 0 (2 loads in flight per wave)
  gl_lds16(kp, dK[0]);
  gl_lds16(vp, dV[0]);

  bf16x8 vones;
  #pragma unroll
  for (int e = 0; e < 8; ++e) vones[e] = __builtin_bit_cast(__bf16, (u16)0x3F80);

  f32x4 oacc[3][4] = {};
  f32x4 osum[3] = {};
  const int c4 = (lg << 2);
  const int xk = lr & 7;

  auto body = [&](int kt, int cur, bool st) {
    if (st) {
      gl_lds16(kp + (size_t)(kt + 1) * 4096, dK[cur ^ 1]);
      gl_lds16(vp + (size_t)(kt + 1) * 64, dV[cur ^ 1]);
      asm volatile("s_waitcnt vmcnt(2)" ::: "memory");  // own-wave cur-tile loads done
    } else {
      asm volatile("s_waitcnt vmcnt(0)" ::: "memory");
    }
    __builtin_amdgcn_sched_barrier(0);
    __builtin_amdgcn_s_barrier();   // B1: all waves' cur-tile data landed

    const uint2 mk = *(const uint2*)(mptr + (kt << 1));
    u32 msk[4][2];
    #pragma unroll
    for (int j = 0; j < 4; ++j) {
      const int c = c4 + j;
      const u32 u0 = (mk.x >> c) & 0x00010001u;
      const u32 u1 = (mk.y >> c) & 0x00010001u;
      msk[j][0] = (u0 << 16) - u0;
      msk[j][1] = (u1 << 16) - u1;
    }

    bf16x8 vb[4][2];
    #pragma unroll
    for (int ct = 0; ct < 4; ++ct) {
      const u16* vrow = &sm.sV[cur][0] + (ct * 16 + lr) * 64;
      vb[ct][0] = *(const bf16x8*)(vrow + (lg ^ xk) * 8);
      vb[ct][1] = *(const bf16x8*)(vrow + ((lg + 4) ^ xk) * 8);
    }

    const f32x4 fz = {0.f, 0.f, 0.f, 0.f};
    auto softpv = [&](f32x4 (&sacc)[4], int s) {
      uint4 pw0, pw1;
      u32* w0 = (u32*)&pw0; u32* w1 = (u32*)&pw1;
      #pragma unroll
      for (int j = 0; j < 4; ++j) {
        w0[j] = cvtpk(rexp2(sacc[0][j]), rexp2(sacc[1][j])) & msk[j][0];
        w1[j] = cvtpk(rexp2(sacc[2][j]), rexp2(sacc[3][j])) & msk[j][1];
      }
      const bf16x8 pa0 = __builtin_bit_cast(bf16x8, pw0);
      const bf16x8 pa1 = __builtin_bit_cast(bf16x8, pw1);
      __builtin_amdgcn_s_setprio(1);
      #pragma unroll
      for (int ct = 0; ct < 4; ++ct) {
        oacc[s][ct] = __builtin_amdgcn_mfma_f32_16x16x32_bf16(pa0, vb[ct][0], oacc[s][ct], 0, 0, 0);
        oacc[s][ct] = __builtin_amdgcn_mfma_f32_16x16x32_bf16(pa1, vb[ct][1], oacc[s][ct], 0, 0, 0);
      }
      osum[s] = __builtin_amdgcn_mfma_f32_16x16x32_bf16(pa0, vones, osum[s], 0, 0, 0);
      osum[s] = __builtin_amdgcn_mfma_f32_16x16x32_bf16(pa1, vones, osum[s], 0, 0, 0);
      __builtin_amdgcn_s_setprio(0);
    };

    {  // segment a
      f32x4 sacc[4];
      __builtin_amdgcn_s_setprio(1);
      #pragma unroll
      for (int t = 0; t < 4; ++t) {
        const bf16x8 kf = *(const bf16x8*)(&sm.sK[cur][0] + (t * 16 + lr) * 64 + ((lg ^ xk) * 8));
        sacc[t] = __builtin_amdgcn_mfma_f32_16x16x32_bf16(kf, qf_a, fz, 0, 0, 0);
      }
      __builtin_amdgcn_s_setprio(0);
      softpv(sacc, 0);
    }
    {  // segment p
      f32x4 sacc[4];
      __builtin_amdgcn_s_setprio(1);
      #pragma unroll
      for (int t = 0; t < 4; ++t) {
        const bf16x8 kf = *(const bf16x8*)(&sm.sK[cur][0] + (t * 16 + lr) * 64 + (((lg + 4) ^ xk) * 8));
        sacc[t] = __builtin_amdgcn_mfma_f32_16x16x32_bf16(kf, qf_p, fz, 0, 0, 0);
      }
      __builtin_amdgcn_s_setprio(0);
      softpv(sacc, 1);
    }
    {  // segment k
      f32x4 sacc[4];
      __builtin_amdgcn_s_setprio(1);
      #pragma unroll
      for (int t = 0; t < 4; ++t) {
        const bf16x8 kf = *(const bf16x8*)(&sm.sK[cur][0] + (t * 16 + lr) * 64 + (((lg + 4) ^ xk) * 8));
        sacc[t] = __builtin_amdgcn_mfma_f32_16x16x32_bf16(kf, qf_k, fz, 0, 0, 0);
      }
      __builtin_amdgcn_s_setprio(0);
      softpv(sacc, 2);
    }

    __builtin_amdgcn_s_barrier();   // B2: all waves done reading buf[cur]
  };

  #pragma unroll 1
  for (int it = 0; it < 16; ++it) {
    body(2 * it, 0, true);
    body(2 * it + 1, 1, it < 15);
  }

  float linv[3][4];
  #pragma unroll
  for (int s = 0; s < 3; ++s)
    #pragma unroll
    for (int j = 0; j < 4; ++j)
      linv[s][j] = 1.0f / (3.0f * osum[s][j] + 1e-30f);

  #pragma unroll
  for (int ct = 0; ct < 4; ++ct) {
    float vj[4];
    #pragma unroll
    for (int j = 0; j < 4; ++j)
      vj[j] = oacc[0][ct][j] * linv[0][j]
            + oacc[1][ct][j] * linv[1][j]
            + oacc[2][ct][j] * linv[2][j];
    const u32 r01 = cvtpk(vj[0], vj[1]);
    const u32 r23 = cvtpk(vj[2], vj[3]);
    const u16 bvv[4] = {(u16)r01, (u16)(r01 >> 16), (u16)r23, (u16)(r23 >> 16)};
    #pragma unroll
    for (int j = 0; j < 4; ++j) {
      const int row = q0 + w * 16 + lg * 4 + j;
      const int col = h * 64 + ct * 16 + lr;
      aout[((size_t)b * 2048 + row) * 512 + col] = bvv[j];
    }
  }
}

// ---------- kernel 3: output projection, M64xN64 tiles ----------
__global__ __launch_bounds__(256) void out_gemm_kernel(
    const u16* __restrict__ A, const u16* __restrict__ Wo,
    const float* __restrict__ bias, float* __restrict__ out) {
  __shared__ u16 lA[64 * 64];
  __shared__ u16 lB[64 * 64];

  const int tid = threadIdx.x;
  const int w = tid >> 6, l = tid & 63;
  const int lr = l & 15, lg = l >> 4;

  const int wg = blockIdx.x;
  const int xcd = wg & 7;
  const int q = wg >> 3;
  const int mt = (xcd << 4) + (q >> 3);
  const int nt = q & 7;
  const int col0 = nt * 64;
  const int m0 = mt * 64;
  f32x4 acc[4] = {};
  const int ubase = tid & ~63;

  #pragma unroll 1
  for (int kt = 0; kt < 8; ++kt) {
    const int k0 = kt << 6;
    #pragma unroll
    for (int i = 0; i < 2; ++i) {
      const int ch = i * 256 + tid;
      const int row = ch >> 3, c8 = (ch & 7) << 3;
      gl_lds16(A + (size_t)(m0 + row) * 512 + k0 + c8, lA + (size_t)(i * 256 + ubase) * 8);
    }
    #pragma unroll
    for (int i = 0; i < 2; ++i) {
      const int ch = i * 256 + tid;
      const int row = ch >> 3, c8 = (ch & 7) << 3;
      gl_lds16(Wo + (size_t)(col0 + row) * 512 + k0 + c8, lB + (size_t)(i * 256 + ubase) * 8);
    }
    __syncthreads();
    bf16x8 af[4][2], bfr[2];
    #pragma unroll
    for (int mi = 0; mi < 4; ++mi) {
      af[mi][0] = *(const bf16x8*)(lA + (mi * 16 + lr) * 64 + lg * 8);
      af[mi][1] = *(const bf16x8*)(lA + (mi * 16 + lr) * 64 + 32 + lg * 8);
    }
    bfr[0] = *(const bf16x8*)(lB + (w * 16 + lr) * 64 + lg * 8);
    bfr[1] = *(const bf16x8*)(lB + (w * 16 + lr) * 64 + 32 + lg * 8);
    #pragma unroll
    for (int mi = 0; mi < 4; ++mi) {
      acc[mi] = __builtin_amdgcn_mfma_f32_16x16x32_bf16(af[mi][0], bfr[0], acc[mi], 0, 0, 0);
      acc[mi] = __builtin_amdgcn_mfma_f32_16x16x32_bf16(af[mi][1], bfr[1], acc[mi], 0, 0, 0);
    }
    __syncthreads();
  }

  const int c = col0 + w * 16 + lr;
  const float bv = bias[c];
  #pragma unroll
  for (int mi = 0; mi < 4; ++mi)
    #pragma unroll
    for (int j = 0; j < 4; ++j) {
      const int m = m0 + mi * 16 + lg * 4 + j;
      out[(size_t)m * 512 + c] = acc[mi][j] + bv;
    }
}

// ---------- launcher ----------
extern "C" void kernel_launch(void* const* d_in, const int* in_sizes, int n_in,
                              void* d_out, int out_size, void* d_ws, size_t ws_size,
                              hipStream_t stream) {
  const float* x    = (const float*)d_in[0];
  const float* Wa   = (const float*)d_in[1];
  const float* Wp   = (const float*)d_in[2];
  const float* Wk   = (const float*)d_in[3];
  const float* Wo   = (const float*)d_in[4];
  const float* bo   = (const float*)d_in[5];
  const int* mask   = (const int*)d_in[6];
  float* out = (float*)d_out;

  char* ws = (char*)d_ws;
  u16* Wab = (u16*)ws;                    //  3,145,728 B
  u16* Wpb = (u16*)(ws + 3145728);        //    786,432 B
  u16* Wkb = (u16*)(ws + 3932160);        //    786,432 B
  u16* Wob = (u16*)(ws + 4718592);        //    524,288 B
  u16* Qb  = (u16*)(ws + 5242880);        //  8,388,608 B  [B,H,N,64] bf16
  u16* Kb  = (u16*)(ws + 13631488);       //  8,388,608 B  [B,H,N,64] bf16
  u16* Vt  = (u16*)(ws + 22020096);       //  8,388,608 B  [B*H,64,2048] bf16 (sigma-perm)
  u64* Mb  = (u64*)(ws + 30408704);       //  2,097,152 B  bitmask
  u16* Ao  = (u16*)(ws + 32505856);       //  8,388,608 B  Vb (n-major V) then attn out
  u16* xb  = (u16*)(ws + 40894464);       // 67,108,864 B  x bf16 (optional)
  u16* Vb  = Ao;                          // alias: V n-major, dead after vtr

  const bool use_xb = ws_size >= (size_t)40894464 + 67108864;
  const int xblocks = use_xb ? 8192 : 0;

  prep_kernel<<<xblocks + 2560 + 1024, 256, 0, stream>>>(
      x, xb, Wa, Wp, Wk, Wo, Wab, Wpb, Wkb, Wob, mask, (u64*)Mb, xblocks);
  if (use_xb) {
    qkv_gemm_kernel<<<1536, 256, 0, stream>>>(xb, Wab, Wpb, Wkb, Qb, Kb, Vb);
  } else {
    qkv_gemm_f32_kernel<<<768, 256, 0, stream>>>(x, Wab, Wpb, Wkb, Qb, Kb, Vb);
  }
  vtr_kernel<<<1024, 256, 0, stream>>>(Vb, Vt);
  attn_kernel<<<512, 512, 0, stream>>>(Qb, Kb, Vt, (const u32*)Mb, Ao);
  out_gemm_kernel<<<1024, 256, 0, stream>>>(Ao, Wob, bo, out);
}

// Round 18
// 267.946 us; speedup vs baseline: 1.0820x; 1.0383x over previous
//
#include <hip/hip_runtime.h>
#include <hip/hip_bf16.h>

typedef __attribute__((ext_vector_type(8))) __bf16 bf16x8;
typedef __attribute__((ext_vector_type(4))) float f32x4;
typedef unsigned short u16;
typedef unsigned int u32;
typedef unsigned long long u64;

// ---------- helpers ----------
__device__ __forceinline__ u32 cvtpk(float lo, float hi) {  // {bf16(lo) | bf16(hi)<<16}
  u32 r;
  asm("v_cvt_pk_bf16_f32 %0, %1, %2" : "=v"(r) : "v"(lo), "v"(hi));
  return r;
}
__device__ __forceinline__ float rexp2(float x) {           // raw v_exp_f32 (2^x)
  float r;
  asm("v_exp_f32 %0, %1" : "=v"(r) : "v"(x));
  return r;
}
__device__ __forceinline__ void gl_lds16(const void* g, void* l) {
  __builtin_amdgcn_global_load_lds((const __attribute__((address_space(1))) void*)g,
                                   (__attribute__((address_space(3))) void*)l, 16, 0, 0);
}
__device__ __forceinline__ int sigma_inv(int n) {           // V key permutation (64-block)
  return ((n >> 5) << 5) | (((n & 15) >> 2) << 3) | ((n & 3) << 1) | ((n >> 4) & 1);
}

// ---------- kernel P: fused prep (xcvt | wcvt | maskbits) ----------
__global__ __launch_bounds__(256) void prep_kernel(
    const float* __restrict__ x, u16* __restrict__ xb,
    const float* __restrict__ Wa, const float* __restrict__ Wp,
    const float* __restrict__ Wk, const float* __restrict__ Wo,
    u16* __restrict__ Wab, u16* __restrict__ Wpb,
    u16* __restrict__ Wkb, u16* __restrict__ Wob,
    const int* __restrict__ mask, u64* __restrict__ bits, int xblocks) {
  int bid = blockIdx.x;
  if (bid < xblocks) {                       // ---- xcvt ----
    const int idx = (bid * 256 + threadIdx.x) * 16;
    const float4 a0 = *(const float4*)(x + idx);
    const float4 a1 = *(const float4*)(x + idx + 4);
    const float4 a2 = *(const float4*)(x + idx + 8);
    const float4 a3 = *(const float4*)(x + idx + 12);
    uint4 t0, t1;
    t0.x = cvtpk(a0.x, a0.y); t0.y = cvtpk(a0.z, a0.w);
    t0.z = cvtpk(a1.x, a1.y); t0.w = cvtpk(a1.z, a1.w);
    t1.x = cvtpk(a2.x, a2.y); t1.y = cvtpk(a2.z, a2.w);
    t1.z = cvtpk(a3.x, a3.y); t1.w = cvtpk(a3.z, a3.w);
    *(uint4*)(xb + idx) = t0;
    *(uint4*)(xb + idx + 8) = t1;
    return;
  }
  bid -= xblocks;
  if (bid < 2560) {                          // ---- wcvt ----
    const float* s; u16* d; int base;
    if (bid < 1536)      { s = Wa; d = Wab; base = bid; }
    else if (bid < 1920) { s = Wp; d = Wpb; base = bid - 1536; }
    else if (bid < 2304) { s = Wk; d = Wkb; base = bid - 1920; }
    else                 { s = Wo; d = Wob; base = bid - 2304; }
    const int idx = (base * 256 + threadIdx.x) * 4;
    const float4 v = *(const float4*)(s + idx);
    *(uint2*)(d + idx) = make_uint2(cvtpk(v.x, v.y), cvtpk(v.z, v.w));
    return;
  }
  bid -= 2560;                               // ---- maskbits ----
  const int lane = threadIdx.x & 63;
  const long long gw = (long long)bid * 4 + (threadIdx.x >> 6);
  const long long nwaves = 1024LL * 4;
  const long long nwords = 16777216LL / 64;
  for (long long i = gw; i < nwords; i += nwaves) {
    const int m = mask[i * 64 + lane];
    const u64 bal = __ballot(m > 0);
    if (lane == 0) bits[i] = bal;
  }
}

// ---------- QKV Q/K store (V handled in-kernel by transpose epilogue) ----------
// Q,K: [B,H,N,64] bf16, segments a@0(32), p@32(16), k@48(16).
// Q PRE-SCALED by (branch D)^-0.5 * log2(e).
__device__ __forceinline__ void qk_store(
    float v0, float v1, float v2, float v3, int m_base, int c,
    int dhs, int seg, float fs,
    u16* __restrict__ Qb, u16* __restrict__ Kb) {
  const int which = c >> (3 + dhs);
  const float f = (which == 0) ? fs : 1.0f;
  const u32 r01 = cvtpk(v0 * f, v1 * f);
  const u32 r23 = cvtpk(v2 * f, v3 * f);
  const u16 bvv[4] = {(u16)r01, (u16)(r01 >> 16), (u16)r23, (u16)(r23 >> 16)};
  const int hd_mask = (8 << dhs) - 1;
  const int r = c & hd_mask;
  const int hh = r >> dhs;
  const int d = r & ((1 << dhs) - 1);
  #pragma unroll
  for (int j = 0; j < 4; ++j) {
    const int m = m_base + j;
    const int bb = m >> 11, n = m & 2047;
    const size_t bhn = (size_t)(bb * 8 + hh) * 2048 + n;
    const u16 bv = bvv[j];
    if (which == 0) Qb[bhn * 64 + seg + d] = bv;
    else            Kb[bhn * 64 + seg + d] = bv;
  }
}

// ---------- kernel 1a: QKV GEMM bf16, M64xN128 tiles ----------
// V-producing block types (nt in {4,5,8,11}) are PURE-V: epilogue does an LDS
// sigma-transpose and writes Vt[bh*64+d][n] directly (no vtr kernel, no Vb).
__global__ __launch_bounds__(256) void qkv_gemm_kernel(
    const u16* __restrict__ xb, const u16* __restrict__ Wa,
    const u16* __restrict__ Wp, const u16* __restrict__ Wk,
    u16* __restrict__ Qb, u16* __restrict__ Kb, u16* __restrict__ Vt) {
  __shared__ u16 smem[64 * 64 + 128 * 64];   // 24 KB; V epilogue reuses as lt[128][72]
  u16* lA = smem;
  u16* lB = smem + 64 * 64;

  const int tid = threadIdx.x;
  const int w = tid >> 6, l = tid & 63;
  const int lr = l & 15, lg = l >> 4;

  const int wg = blockIdx.x;
  const int xcd = wg & 7;
  const int q = wg >> 3;
  const int mtl = q / 12, nt = q % 12;
  const int mt = (xcd << 4) + mtl;

  const u16* W; int xoff, Kd, col0, dhs, seg;
  if (nt < 6)      { W = Wa; xoff = 0;    Kd = 2048; col0 = nt * 128;       dhs = 5; seg = 0;  }
  else if (nt < 9) { W = Wp; xoff = 2048; Kd = 1024; col0 = (nt - 6) * 128; dhs = 4; seg = 32; }
  else             { W = Wk; xoff = 3072; Kd = 1024; col0 = (nt - 9) * 128; dhs = 4; seg = 48; }
  const float qscale = (dhs == 5) ? 0.031880107f : 0.045084220f;  // D^-0.5 * log2(e)
  const bool isV = (nt == 4) | (nt == 5) | (nt == 8) | (nt == 11);

  const int m0 = mt * 64;
  f32x4 acc[4][2] = {};
  const int ubase = tid & ~63;

  const int nk = Kd >> 6;
  #pragma unroll 1
  for (int kt = 0; kt < nk; ++kt) {
    const int k0 = kt << 6;
    #pragma unroll
    for (int i = 0; i < 2; ++i) {
      const int ch = i * 256 + tid;
      const int row = ch >> 3, c8 = (ch & 7) << 3;
      gl_lds16(xb + (size_t)(m0 + row) * 4096 + xoff + k0 + c8,
               lA + (size_t)(i * 256 + ubase) * 8);
    }
    #pragma unroll
    for (int i = 0; i < 4; ++i) {
      const int ch = i * 256 + tid;
      const int row = ch >> 3, c8 = (ch & 7) << 3;
      gl_lds16(W + (size_t)(col0 + row) * Kd + k0 + c8,
               lB + (size_t)(i * 256 + ubase) * 8);
    }
    __syncthreads();
    bf16x8 af[4][2], bfr[2][2];
    #pragma unroll
    for (int mi = 0; mi < 4; ++mi) {
      af[mi][0] = *(const bf16x8*)(lA + (mi * 16 + lr) * 64 + lg * 8);
      af[mi][1] = *(const bf16x8*)(lA + (mi * 16 + lr) * 64 + 32 + lg * 8);
    }
    #pragma unroll
    for (int ni = 0; ni < 2; ++ni) {
      bfr[ni][0] = *(const bf16x8*)(lB + (w * 32 + ni * 16 + lr) * 64 + lg * 8);
      bfr[ni][1] = *(const bf16x8*)(lB + (w * 32 + ni * 16 + lr) * 64 + 32 + lg * 8);
    }
    #pragma unroll
    for (int mi = 0; mi < 4; ++mi)
      #pragma unroll
      for (int ni = 0; ni < 2; ++ni) {
        acc[mi][ni] = __builtin_amdgcn_mfma_f32_16x16x32_bf16(af[mi][0], bfr[ni][0], acc[mi][ni], 0, 0, 0);
        acc[mi][ni] = __builtin_amdgcn_mfma_f32_16x16x32_bf16(af[mi][1], bfr[ni][1], acc[mi][ni], 0, 0, 0);
      }
    __syncthreads();
  }

  if (!isV) {
    #pragma unroll
    for (int mi = 0; mi < 4; ++mi)
      #pragma unroll
      for (int ni = 0; ni < 2; ++ni)
        qk_store(acc[mi][ni][0], acc[mi][ni][1], acc[mi][ni][2], acc[mi][ni][3],
                 m0 + mi * 16 + lg * 4, col0 + w * 32 + ni * 16 + lr,
                 dhs, seg, qscale, Qb, Kb);
  } else {
    // sigma-transpose via LDS: lt[c 0..127][pos 0..63] stride 72
    #pragma unroll
    for (int mi = 0; mi < 4; ++mi)
      #pragma unroll
      for (int ni = 0; ni < 2; ++ni) {
        const u32 r01 = cvtpk(acc[mi][ni][0], acc[mi][ni][1]);
        const u32 r23 = cvtpk(acc[mi][ni][2], acc[mi][ni][3]);
        const u16 bvv[4] = {(u16)r01, (u16)(r01 >> 16), (u16)r23, (u16)(r23 >> 16)};
        const int cl = w * 32 + ni * 16 + lr;
        #pragma unroll
        for (int j = 0; j < 4; ++j) {
          const int n = mi * 16 + lg * 4 + j;
          smem[cl * 72 + sigma_inv(n)] = bvv[j];
        }
      }
    __syncthreads();
    const int c = tid >> 1, half = (tid & 1) << 5;
    const int hd_mask = (8 << dhs) - 1;
    const int r = (col0 + c) & hd_mask;
    const int hh = r >> dhs, d = r & ((1 << dhs) - 1);
    const int bb = m0 >> 11, n0v = m0 & 2047;
    u16* dst = Vt + ((size_t)(bb * 8 + hh) * 64 + seg + d) * 2048 + n0v + half;
    const u16* srcl = smem + c * 72 + half;
    #pragma unroll
    for (int e = 0; e < 4; ++e)
      *(uint4*)(dst + e * 8) = *(const uint4*)(srcl + e * 8);
  }
}

// ---------- kernel 1b: fallback, x fp32 reg-staged (writes Vt scattered) ----------
__global__ __launch_bounds__(256) void qkv_gemm_f32_kernel(
    const float* __restrict__ x, const u16* __restrict__ Wa,
    const u16* __restrict__ Wp, const u16* __restrict__ Wk,
    u16* __restrict__ Qb, u16* __restrict__ Kb, u16* __restrict__ Vt) {
  __shared__ u16 lA[128 * 64];
  __shared__ u16 lB[128 * 64];

  const int tid = threadIdx.x;
  const int w = tid >> 6, l = tid & 63;
  const int lr = l & 15, lg = l >> 4;
  const int wr = w >> 1, wc = w & 1;

  const int wg = blockIdx.x;
  const int xcd = wg & 7;
  const int q = wg >> 3;
  const int mtl = q / 12, nt = q % 12;
  const int mt = (xcd << 3) + mtl;

  const u16* W; int xoff, Kd, col0, dhs, seg;
  if (nt < 6)      { W = Wa; xoff = 0;    Kd = 2048; col0 = nt * 128;       dhs = 5; seg = 0;  }
  else if (nt < 9) { W = Wp; xoff = 2048; Kd = 1024; col0 = (nt - 6) * 128; dhs = 4; seg = 32; }
  else             { W = Wk; xoff = 3072; Kd = 1024; col0 = (nt - 9) * 128; dhs = 4; seg = 48; }
  const float qscale = (dhs == 5) ? 0.031880107f : 0.045084220f;

  const int m0 = mt * 128;
  f32x4 acc[4][4] = {};
  const int ubase = tid & ~63;

  const int nk = Kd >> 6;
  #pragma unroll 1
  for (int kt = 0; kt < nk; ++kt) {
    const int k0 = kt << 6;
    #pragma unroll
    for (int i = 0; i < 4; ++i) {
      const int ch = i * 256 + tid;
      const int row = ch >> 3, c8 = (ch & 7) << 3;
      const float* src = x + (size_t)(m0 + row) * 4096 + xoff + k0 + c8;
      const float4 a0 = *(const float4*)(src);
      const float4 a1 = *(const float4*)(src + 4);
      uint4 t;
      t.x = cvtpk(a0.x, a0.y); t.y = cvtpk(a0.z, a0.w);
      t.z = cvtpk(a1.x, a1.y); t.w = cvtpk(a1.z, a1.w);
      *(uint4*)(lA + (size_t)row * 64 + c8) = t;
    }
    #pragma unroll
    for (int i = 0; i < 4; ++i) {
      const int ch = i * 256 + tid;
      const int row = ch >> 3, c8 = (ch & 7) << 3;
      gl_lds16(W + (size_t)(col0 + row) * Kd + k0 + c8,
               lB + (size_t)(i * 256 + ubase) * 8);
    }
    __syncthreads();
    bf16x8 af[4][2], bfr[4][2];
    #pragma unroll
    for (int mi = 0; mi < 4; ++mi) {
      af[mi][0] = *(const bf16x8*)(lA + (wr * 64 + mi * 16 + lr) * 64 + lg * 8);
      af[mi][1] = *(const bf16x8*)(lA + (wr * 64 + mi * 16 + lr) * 64 + 32 + lg * 8);
    }
    #pragma unroll
    for (int ni = 0; ni < 4; ++ni) {
      bfr[ni][0] = *(const bf16x8*)(lB + (wc * 64 + ni * 16 + lr) * 64 + lg * 8);
      bfr[ni][1] = *(const bf16x8*)(lB + (wc * 64 + ni * 16 + lr) * 64 + 32 + lg * 8);
    }
    #pragma unroll
    for (int mi = 0; mi < 4; ++mi)
      #pragma unroll
      for (int ni = 0; ni < 4; ++ni) {
        acc[mi][ni] = __builtin_amdgcn_mfma_f32_16x16x32_bf16(af[mi][0], bfr[ni][0], acc[mi][ni], 0, 0, 0);
        acc[mi][ni] = __builtin_amdgcn_mfma_f32_16x16x32_bf16(af[mi][1], bfr[ni][1], acc[mi][ni], 0, 0, 0);
      }
    __syncthreads();
  }
  #pragma unroll
  for (int mi = 0; mi < 4; ++mi)
    #pragma unroll
    for (int ni = 0; ni < 4; ++ni) {
      const int c = col0 + wc * 64 + ni * 16 + lr;
      const int which = c >> (3 + dhs);
      const float f = (which == 0) ? qscale : 1.0f;
      const u32 r01 = cvtpk(acc[mi][ni][0] * f, acc[mi][ni][1] * f);
      const u32 r23 = cvtpk(acc[mi][ni][2] * f, acc[mi][ni][3] * f);
      const u16 bvv[4] = {(u16)r01, (u16)(r01 >> 16), (u16)r23, (u16)(r23 >> 16)};
      const int hd_mask = (8 << dhs) - 1;
      const int r = c & hd_mask;
      const int hh = r >> dhs;
      const int d = r & ((1 << dhs) - 1);
      #pragma unroll
      for (int j = 0; j < 4; ++j) {
        const int m = m0 + wr * 64 + mi * 16 + lg * 4 + j;
        const int bb = m >> 11, n = m & 2047;
        const size_t bhn = (size_t)(bb * 8 + hh) * 2048 + n;
        const u16 bv = bvv[j];
        if (which == 0)      Qb[bhn * 64 + seg + d] = bv;
        else if (which == 1) Kb[bhn * 64 + seg + d] = bv;
        else Vt[((size_t)(bb * 8 + hh) * 64 + seg + d) * 2048 + (n & ~63) + sigma_inv(n & 63)] = bv;
      }
    }
}

// ---------- kernel 2: fused 3-branch flash attention ----------
// QBLK=128 (512 thr): 1 K + 1 V gl_lds per wave per tile; counted vmcnt dbuf,
// manual 2x unroll. NEW: mask prefetched one tile ahead (off critical path);
// vmcnt(3) = {mask,K,V} of next tile in flight.
__global__ __launch_bounds__(512) void attn_kernel(
    const u16* __restrict__ Qb, const u16* __restrict__ Kb,
    const u16* __restrict__ Vt, const u32* __restrict__ mbits,
    u16* __restrict__ aout) {
  struct SMem {
    u16 sK[2][64 * 64];   // 2 x 8192 B
    u16 sV[2][64 * 64];   // 2 x 8192 B
  };
  __shared__ SMem sm;     // 32768 B

  const int tid = threadIdx.x;
  const int w = tid >> 6, l = tid & 63;
  const int lr = l & 15, lg = l >> 4;
  const int wg = blockIdx.x;            // 0..511
  const int xcd = wg & 7, rr0 = wg >> 3;
  const int bh = (xcd << 2) + (rr0 >> 4);   // each XCD: 4 bh x 16 qt
  const int qt = rr0 & 15;
  const int b = bh >> 3, h = bh & 7;
  const int q0 = qt << 7;               // 128 q-rows per block
  const size_t bhN = (size_t)bh * 2048;
  const int ubase = tid & ~63;

  const u16* qrow = Qb + (bhN + q0 + w * 16 + lr) * 64;
  const bf16x8 qf_a  = *(const bf16x8*)(qrow + lg * 8);
  const bf16x8 qf_pk = *(const bf16x8*)(qrow + 32 + lg * 8);
  bf16x8 zero8 = {};
  const bf16x8 qf_p = (lg < 2) ? qf_pk : zero8;
  const bf16x8 qf_k = (lg < 2) ? zero8 : qf_pk;

  const u32* mptr = mbits + ((size_t)b * 2048 + q0 + w * 16 + lr) * 64;

  const int sr = tid >> 3, swd = tid & 7;
  const u16* kp = Kb + (bhN + sr) * 64 + (swd ^ (sr & 7)) * 8;          // + kt*4096
  const u16* vp = Vt + ((size_t)bh * 64 + sr) * 2048 + (swd ^ (sr & 7)) * 8;  // + kt*64
  u16* dK[2] = { &sm.sK[0][0] + ubase * 8, &sm.sK[1][0] + ubase * 8 };
  u16* dV[2] = { &sm.sV[0][0] + ubase * 8, &sm.sV[1][0] + ubase * 8 };

  uint2 mkA = *(const uint2*)(mptr);   // tile 0 mask (prefetched)
  uint2 mkB;
  gl_lds16(kp, dK[0]);
  gl_lds16(vp, dV[0]);

  bf16x8 vones;
  #pragma unroll
  for (int e = 0; e < 8; ++e) vones[e] = __builtin_bit_cast(__bf16, (u16)0x3F80);

  f32x4 oacc[3][4] = {};
  f32x4 osum[3] = {};
  const int c4 = (lg << 2);
  const int xk = lr & 7;

  auto body = [&](int kt, int cur, bool st, uint2 mkv, uint2* mknext) {
    if (st) {
      *mknext = *(const uint2*)(mptr + ((kt + 1) << 1));   // mask prefetch (kt+1)
      gl_lds16(kp + (size_t)(kt + 1) * 4096, dK[cur ^ 1]);
      gl_lds16(vp + (size_t)(kt + 1) * 64, dV[cur ^ 1]);
      asm volatile("s_waitcnt vmcnt(3)" ::: "memory");  // cur K/V landed (3 newest in flight)
    } else {
      asm volatile("s_waitcnt vmcnt(0)" ::: "memory");
    }
    __builtin_amdgcn_sched_barrier(0);
    __builtin_amdgcn_s_barrier();   // B1: all waves' cur-tile data landed

    u32 msk[4][2];
    #pragma unroll
    for (int j = 0; j < 4; ++j) {
      const int c = c4 + j;
      const u32 u0 = (mkv.x >> c) & 0x00010001u;
      const u32 u1 = (mkv.y >> c) & 0x00010001u;
      msk[j][0] = (u0 << 16) - u0;
      msk[j][1] = (u1 << 16) - u1;
    }

    bf16x8 vb[4][2];
    #pragma unroll
    for (int ct = 0; ct < 4; ++ct) {
      const u16* vrow = &sm.sV[cur][0] + (ct * 16 + lr) * 64;
      vb[ct][0] = *(const bf16x8*)(vrow + (lg ^ xk) * 8);
      vb[ct][1] = *(const bf16x8*)(vrow + ((lg + 4) ^ xk) * 8);
    }

    const f32x4 fz = {0.f, 0.f, 0.f, 0.f};
    auto softpv = [&](f32x4 (&sacc)[4], int s) {
      uint4 pw0, pw1;
      u32* w0 = (u32*)&pw0; u32* w1 = (u32*)&pw1;
      #pragma unroll
      for (int j = 0; j < 4; ++j) {
        w0[j] = cvtpk(rexp2(sacc[0][j]), rexp2(sacc[1][j])) & msk[j][0];
        w1[j] = cvtpk(rexp2(sacc[2][j]), rexp2(sacc[3][j])) & msk[j][1];
      }
      const bf16x8 pa0 = __builtin_bit_cast(bf16x8, pw0);
      const bf16x8 pa1 = __builtin_bit_cast(bf16x8, pw1);
      __builtin_amdgcn_s_setprio(1);
      #pragma unroll
      for (int ct = 0; ct < 4; ++ct) {
        oacc[s][ct] = __builtin_amdgcn_mfma_f32_16x16x32_bf16(pa0, vb[ct][0], oacc[s][ct], 0, 0, 0);
        oacc[s][ct] = __builtin_amdgcn_mfma_f32_16x16x32_bf16(pa1, vb[ct][1], oacc[s][ct], 0, 0, 0);
      }
      osum[s] = __builtin_amdgcn_mfma_f32_16x16x32_bf16(pa0, vones, osum[s], 0, 0, 0);
      osum[s] = __builtin_amdgcn_mfma_f32_16x16x32_bf16(pa1, vones, osum[s], 0, 0, 0);
      __builtin_amdgcn_s_setprio(0);
    };

    {  // segment a
      f32x4 sacc[4];
      __builtin_amdgcn_s_setprio(1);
      #pragma unroll
      for (int t = 0; t < 4; ++t) {
        const bf16x8 kf = *(const bf16x8*)(&sm.sK[cur][0] + (t * 16 + lr) * 64 + ((lg ^ xk) * 8));
        sacc[t] = __builtin_amdgcn_mfma_f32_16x16x32_bf16(kf, qf_a, fz, 0, 0, 0);
      }
      __builtin_amdgcn_s_setprio(0);
      softpv(sacc, 0);
    }
    {  // segment p
      f32x4 sacc[4];
      __builtin_amdgcn_s_setprio(1);
      #pragma unroll
      for (int t = 0; t < 4; ++t) {
        const bf16x8 kf = *(const bf16x8*)(&sm.sK[cur][0] + (t * 16 + lr) * 64 + (((lg + 4) ^ xk) * 8));
        sacc[t] = __builtin_amdgcn_mfma_f32_16x16x32_bf16(kf, qf_p, fz, 0, 0, 0);
      }
      __builtin_amdgcn_s_setprio(0);
      softpv(sacc, 1);
    }
    {  // segment k
      f32x4 sacc[4];
      __builtin_amdgcn_s_setprio(1);
      #pragma unroll
      for (int t = 0; t < 4; ++t) {
        const bf16x8 kf = *(const bf16x8*)(&sm.sK[cur][0] + (t * 16 + lr) * 64 + (((lg + 4) ^ xk) * 8));
        sacc[t] = __builtin_amdgcn_mfma_f32_16x16x32_bf16(kf, qf_k, fz, 0, 0, 0);
      }
      __builtin_amdgcn_s_setprio(0);
      softpv(sacc, 2);
    }

    __builtin_amdgcn_s_barrier();   // B2: all waves done reading buf[cur]
  };

  #pragma unroll 1
  for (int it = 0; it < 16; ++it) {
    body(2 * it, 0, true, mkA, &mkB);
    body(2 * it + 1, 1, it < 15, mkB, &mkA);
  }

  float linv[3][4];
  #pragma unroll
  for (int s = 0; s < 3; ++s)
    #pragma unroll
    for (int j = 0; j < 4; ++j)
      linv[s][j] = 1.0f / (3.0f * osum[s][j] + 1e-30f);

  #pragma unroll
  for (int ct = 0; ct < 4; ++ct) {
    float vj[4];
    #pragma unroll
    for (int j = 0; j < 4; ++j)
      vj[j] = oacc[0][ct][j] * linv[0][j]
            + oacc[1][ct][j] * linv[1][j]
            + oacc[2][ct][j] * linv[2][j];
    const u32 r01 = cvtpk(vj[0], vj[1]);
    const u32 r23 = cvtpk(vj[2], vj[3]);
    const u16 bvv[4] = {(u16)r01, (u16)(r01 >> 16), (u16)r23, (u16)(r23 >> 16)};
    #pragma unroll
    for (int j = 0; j < 4; ++j) {
      const int row = q0 + w * 16 + lg * 4 + j;
      const int col = h * 64 + ct * 16 + lr;
      aout[((size_t)b * 2048 + row) * 512 + col] = bvv[j];
    }
  }
}

// ---------- kernel 3: output projection, M64xN64 tiles ----------
__global__ __launch_bounds__(256) void out_gemm_kernel(
    const u16* __restrict__ A, const u16* __restrict__ Wo,
    const float* __restrict__ bias, float* __restrict__ out) {
  __shared__ u16 lA[64 * 64];
  __shared__ u16 lB[64 * 64];

  const int tid = threadIdx.x;
  const int w = tid >> 6, l = tid & 63;
  const int lr = l & 15, lg = l >> 4;

  const int wg = blockIdx.x;
  const int xcd = wg & 7;
  const int q = wg >> 3;
  const int mt = (xcd << 4) + (q >> 3);
  const int nt = q & 7;
  const int col0 = nt * 64;
  const int m0 = mt * 64;
  f32x4 acc[4] = {};
  const int ubase = tid & ~63;

  #pragma unroll 1
  for (int kt = 0; kt < 8; ++kt) {
    const int k0 = kt << 6;
    #pragma unroll
    for (int i = 0; i < 2; ++i) {
      const int ch = i * 256 + tid;
      const int row = ch >> 3, c8 = (ch & 7) << 3;
      gl_lds16(A + (size_t)(m0 + row) * 512 + k0 + c8, lA + (size_t)(i * 256 + ubase) * 8);
    }
    #pragma unroll
    for (int i = 0; i < 2; ++i) {
      const int ch = i * 256 + tid;
      const int row = ch >> 3, c8 = (ch & 7) << 3;
      gl_lds16(Wo + (size_t)(col0 + row) * 512 + k0 + c8, lB + (size_t)(i * 256 + ubase) * 8);
    }
    __syncthreads();
    bf16x8 af[4][2], bfr[2];
    #pragma unroll
    for (int mi = 0; mi < 4; ++mi) {
      af[mi][0] = *(const bf16x8*)(lA + (mi * 16 + lr) * 64 + lg * 8);
      af[mi][1] = *(const bf16x8*)(lA + (mi * 16 + lr) * 64 + 32 + lg * 8);
    }
    bfr[0] = *(const bf16x8*)(lB + (w * 16 + lr) * 64 + lg * 8);
    bfr[1] = *(const bf16x8*)(lB + (w * 16 + lr) * 64 + 32 + lg * 8);
    #pragma unroll
    for (int mi = 0; mi < 4; ++mi) {
      acc[mi] = __builtin_amdgcn_mfma_f32_16x16x32_bf16(af[mi][0], bfr[0], acc[mi], 0, 0, 0);
      acc[mi] = __builtin_amdgcn_mfma_f32_16x16x32_bf16(af[mi][1], bfr[1], acc[mi], 0, 0, 0);
    }
    __syncthreads();
  }

  const int c = col0 + w * 16 + lr;
  const float bv = bias[c];
  #pragma unroll
  for (int mi = 0; mi < 4; ++mi)
    #pragma unroll
    for (int j = 0; j < 4; ++j) {
      const int m = m0 + mi * 16 + lg * 4 + j;
      out[(size_t)m * 512 + c] = acc[mi][j] + bv;
    }
}

// ---------- launcher ----------
extern "C" void kernel_launch(void* const* d_in, const int* in_sizes, int n_in,
                              void* d_out, int out_size, void* d_ws, size_t ws_size,
                              hipStream_t stream) {
  const float* x    = (const float*)d_in[0];
  const float* Wa   = (const float*)d_in[1];
  const float* Wp   = (const float*)d_in[2];
  const float* Wk   = (const float*)d_in[3];
  const float* Wo   = (const float*)d_in[4];
  const float* bo   = (const float*)d_in[5];
  const int* mask   = (const int*)d_in[6];
  float* out = (float*)d_out;

  char* ws = (char*)d_ws;
  u16* Wab = (u16*)ws;                    //  3,145,728 B
  u16* Wpb = (u16*)(ws + 3145728);        //    786,432 B
  u16* Wkb = (u16*)(ws + 3932160);        //    786,432 B
  u16* Wob = (u16*)(ws + 4718592);        //    524,288 B
  u16* Qb  = (u16*)(ws + 5242880);        //  8,388,608 B  [B,H,N,64] bf16
  u16* Kb  = (u16*)(ws + 13631488);       //  8,388,608 B  [B,H,N,64] bf16
  u16* Vt  = (u16*)(ws + 22020096);       //  8,388,608 B  [B*H,64,2048] bf16 (sigma-perm)
  u64* Mb  = (u64*)(ws + 30408704);       //  2,097,152 B  bitmask
  u16* Ao  = (u16*)(ws + 32505856);       //  8,388,608 B  attn out [B,N,512] bf16
  u16* xb  = (u16*)(ws + 40894464);       // 67,108,864 B  x bf16 (optional)

  const bool use_xb = ws_size >= (size_t)40894464 + 67108864;
  const int xblocks = use_xb ? 8192 : 0;

  prep_kernel<<<xblocks + 2560 + 1024, 256, 0, stream>>>(
      x, xb, Wa, Wp, Wk, Wo, Wab, Wpb, Wkb, Wob, mask, (u64*)Mb, xblocks);
  if (use_xb) {
    qkv_gemm_kernel<<<1536, 256, 0, stream>>>(xb, Wab, Wpb, Wkb, Qb, Kb, Vt);
  } else {
    qkv_gemm_f32_kernel<<<768, 256, 0, stream>>>(x, Wab, Wpb, Wkb, Qb, Kb, Vt);
  }
  attn_kernel<<<512, 512, 0, stream>>>(Qb, Kb, Vt, (const u32*)Mb, Ao);
  out_gemm_kernel<<<1024, 256, 0, stream>>>(Ao, Wob, bo, out);
}

// Round 19
// 262.167 us; speedup vs baseline: 1.1059x; 1.0220x over previous
//
#include <hip/hip_runtime.h>
#include <hip/hip_bf16.h>

typedef __attribute__((ext_vector_type(8))) __bf16 bf16x8;
typedef __attribute__((ext_vector_type(4))) float f32x4;
typedef unsigned short u16;
typedef unsigned int u32;
typedef unsigned long long u64;

// ---------- helpers ----------
__device__ __forceinline__ u32 cvtpk(float lo, float hi) {  // {bf16(lo) | bf16(hi)<<16}
  u32 r;
  asm("v_cvt_pk_bf16_f32 %0, %1, %2" : "=v"(r) : "v"(lo), "v"(hi));
  return r;
}
__device__ __forceinline__ float rexp2(float x) {           // raw v_exp_f32 (2^x)
  float r;
  asm("v_exp_f32 %0, %1" : "=v"(r) : "v"(x));
  return r;
}
__device__ __forceinline__ void gl_lds16(const void* g, void* l) {
  __builtin_amdgcn_global_load_lds((const __attribute__((address_space(1))) void*)g,
                                   (__attribute__((address_space(3))) void*)l, 16, 0, 0);
}
__device__ __forceinline__ int sigma_inv(int n) {           // V key permutation (64-block)
  return ((n >> 5) << 5) | (((n & 15) >> 2) << 3) | ((n & 3) << 1) | ((n >> 4) & 1);
}

// ---------- kernel P: fused prep (xcvt | wcvt | maskbits) ----------
__global__ __launch_bounds__(256) void prep_kernel(
    const float* __restrict__ x, u16* __restrict__ xb,
    const float* __restrict__ Wa, const float* __restrict__ Wp,
    const float* __restrict__ Wk, const float* __restrict__ Wo,
    u16* __restrict__ Wab, u16* __restrict__ Wpb,
    u16* __restrict__ Wkb, u16* __restrict__ Wob,
    const int* __restrict__ mask, u64* __restrict__ bits, int xblocks) {
  int bid = blockIdx.x;
  if (bid < xblocks) {                       // ---- xcvt ----
    const int idx = (bid * 256 + threadIdx.x) * 16;
    const float4 a0 = *(const float4*)(x + idx);
    const float4 a1 = *(const float4*)(x + idx + 4);
    const float4 a2 = *(const float4*)(x + idx + 8);
    const float4 a3 = *(const float4*)(x + idx + 12);
    uint4 t0, t1;
    t0.x = cvtpk(a0.x, a0.y); t0.y = cvtpk(a0.z, a0.w);
    t0.z = cvtpk(a1.x, a1.y); t0.w = cvtpk(a1.z, a1.w);
    t1.x = cvtpk(a2.x, a2.y); t1.y = cvtpk(a2.z, a2.w);
    t1.z = cvtpk(a3.x, a3.y); t1.w = cvtpk(a3.z, a3.w);
    *(uint4*)(xb + idx) = t0;
    *(uint4*)(xb + idx + 8) = t1;
    return;
  }
  bid -= xblocks;
  if (bid < 2560) {                          // ---- wcvt ----
    const float* s; u16* d; int base;
    if (bid < 1536)      { s = Wa; d = Wab; base = bid; }
    else if (bid < 1920) { s = Wp; d = Wpb; base = bid - 1536; }
    else if (bid < 2304) { s = Wk; d = Wkb; base = bid - 1920; }
    else                 { s = Wo; d = Wob; base = bid - 2304; }
    const int idx = (base * 256 + threadIdx.x) * 4;
    const float4 v = *(const float4*)(s + idx);
    *(uint2*)(d + idx) = make_uint2(cvtpk(v.x, v.y), cvtpk(v.z, v.w));
    return;
  }
  bid -= 2560;                               // ---- maskbits ----
  const int lane = threadIdx.x & 63;
  const long long gw = (long long)bid * 4 + (threadIdx.x >> 6);
  const long long nwaves = 1024LL * 4;
  const long long nwords = 16777216LL / 64;
  for (long long i = gw; i < nwords; i += nwaves) {
    const int m = mask[i * 64 + lane];
    const u64 bal = __ballot(m > 0);
    if (lane == 0) bits[i] = bal;
  }
}

// ---------- QKV Q/K store ----------
__device__ __forceinline__ void qk_store(
    float v0, float v1, float v2, float v3, int m_base, int c,
    int dhs, int seg, float fs,
    u16* __restrict__ Qb, u16* __restrict__ Kb) {
  const int which = c >> (3 + dhs);
  const float f = (which == 0) ? fs : 1.0f;
  const u32 r01 = cvtpk(v0 * f, v1 * f);
  const u32 r23 = cvtpk(v2 * f, v3 * f);
  const u16 bvv[4] = {(u16)r01, (u16)(r01 >> 16), (u16)r23, (u16)(r23 >> 16)};
  const int hd_mask = (8 << dhs) - 1;
  const int r = c & hd_mask;
  const int hh = r >> dhs;
  const int d = r & ((1 << dhs) - 1);
  #pragma unroll
  for (int j = 0; j < 4; ++j) {
    const int m = m_base + j;
    const int bb = m >> 11, n = m & 2047;
    const size_t bhn = (size_t)(bb * 8 + hh) * 2048 + n;
    const u16 bv = bvv[j];
    if (which == 0) Qb[bhn * 64 + seg + d] = bv;
    else            Kb[bhn * 64 + seg + d] = bv;
  }
}

// ---------- kernel 1a: QKV GEMM bf16, M64xN128 tiles ----------
// V-producing block types (nt in {4,5,8,11}) are PURE-V: epilogue does an LDS
// sigma-transpose and writes Vt[bh*64+d][n] directly.
__global__ __launch_bounds__(256) void qkv_gemm_kernel(
    const u16* __restrict__ xb, const u16* __restrict__ Wa,
    const u16* __restrict__ Wp, const u16* __restrict__ Wk,
    u16* __restrict__ Qb, u16* __restrict__ Kb, u16* __restrict__ Vt) {
  __shared__ u16 smem[64 * 64 + 128 * 64];   // 24 KB; V epilogue reuses as lt[128][72]
  u16* lA = smem;
  u16* lB = smem + 64 * 64;

  const int tid = threadIdx.x;
  const int w = tid >> 6, l = tid & 63;
  const int lr = l & 15, lg = l >> 4;

  const int wg = blockIdx.x;
  const int xcd = wg & 7;
  const int q = wg >> 3;
  const int mtl = q / 12, nt = q % 12;
  const int mt = (xcd << 4) + mtl;

  const u16* W; int xoff, Kd, col0, dhs, seg;
  if (nt < 6)      { W = Wa; xoff = 0;    Kd = 2048; col0 = nt * 128;       dhs = 5; seg = 0;  }
  else if (nt < 9) { W = Wp; xoff = 2048; Kd = 1024; col0 = (nt - 6) * 128; dhs = 4; seg = 32; }
  else             { W = Wk; xoff = 3072; Kd = 1024; col0 = (nt - 9) * 128; dhs = 4; seg = 48; }
  const float qscale = (dhs == 5) ? 0.031880107f : 0.045084220f;  // D^-0.5 * log2(e)
  const bool isV = (nt == 4) | (nt == 5) | (nt == 8) | (nt == 11);

  const int m0 = mt * 64;
  f32x4 acc[4][2] = {};
  const int ubase = tid & ~63;

  const int nk = Kd >> 6;
  #pragma unroll 1
  for (int kt = 0; kt < nk; ++kt) {
    const int k0 = kt << 6;
    #pragma unroll
    for (int i = 0; i < 2; ++i) {
      const int ch = i * 256 + tid;
      const int row = ch >> 3, c8 = (ch & 7) << 3;
      gl_lds16(xb + (size_t)(m0 + row) * 4096 + xoff + k0 + c8,
               lA + (size_t)(i * 256 + ubase) * 8);
    }
    #pragma unroll
    for (int i = 0; i < 4; ++i) {
      const int ch = i * 256 + tid;
      const int row = ch >> 3, c8 = (ch & 7) << 3;
      gl_lds16(W + (size_t)(col0 + row) * Kd + k0 + c8,
               lB + (size_t)(i * 256 + ubase) * 8);
    }
    __syncthreads();
    bf16x8 af[4][2], bfr[2][2];
    #pragma unroll
    for (int mi = 0; mi < 4; ++mi) {
      af[mi][0] = *(const bf16x8*)(lA + (mi * 16 + lr) * 64 + lg * 8);
      af[mi][1] = *(const bf16x8*)(lA + (mi * 16 + lr) * 64 + 32 + lg * 8);
    }
    #pragma unroll
    for (int ni = 0; ni < 2; ++ni) {
      bfr[ni][0] = *(const bf16x8*)(lB + (w * 32 + ni * 16 + lr) * 64 + lg * 8);
      bfr[ni][1] = *(const bf16x8*)(lB + (w * 32 + ni * 16 + lr) * 64 + 32 + lg * 8);
    }
    #pragma unroll
    for (int mi = 0; mi < 4; ++mi)
      #pragma unroll
      for (int ni = 0; ni < 2; ++ni) {
        acc[mi][ni] = __builtin_amdgcn_mfma_f32_16x16x32_bf16(af[mi][0], bfr[ni][0], acc[mi][ni], 0, 0, 0);
        acc[mi][ni] = __builtin_amdgcn_mfma_f32_16x16x32_bf16(af[mi][1], bfr[ni][1], acc[mi][ni], 0, 0, 0);
      }
    __syncthreads();
  }

  if (!isV) {
    #pragma unroll
    for (int mi = 0; mi < 4; ++mi)
      #pragma unroll
      for (int ni = 0; ni < 2; ++ni)
        qk_store(acc[mi][ni][0], acc[mi][ni][1], acc[mi][ni][2], acc[mi][ni][3],
                 m0 + mi * 16 + lg * 4, col0 + w * 32 + ni * 16 + lr,
                 dhs, seg, qscale, Qb, Kb);
  } else {
    // sigma-transpose via LDS: lt[c 0..127][pos 0..63] stride 72
    #pragma unroll
    for (int mi = 0; mi < 4; ++mi)
      #pragma unroll
      for (int ni = 0; ni < 2; ++ni) {
        const u32 r01 = cvtpk(acc[mi][ni][0], acc[mi][ni][1]);
        const u32 r23 = cvtpk(acc[mi][ni][2], acc[mi][ni][3]);
        const u16 bvv[4] = {(u16)r01, (u16)(r01 >> 16), (u16)r23, (u16)(r23 >> 16)};
        const int cl = w * 32 + ni * 16 + lr;
        #pragma unroll
        for (int j = 0; j < 4; ++j) {
          const int n = mi * 16 + lg * 4 + j;
          smem[cl * 72 + sigma_inv(n)] = bvv[j];
        }
      }
    __syncthreads();
    const int c = tid >> 1, half = (tid & 1) << 5;
    const int hd_mask = (8 << dhs) - 1;
    const int r = (col0 + c) & hd_mask;
    const int hh = r >> dhs, d = r & ((1 << dhs) - 1);
    const int bb = m0 >> 11, n0v = m0 & 2047;
    u16* dst = Vt + ((size_t)(bb * 8 + hh) * 64 + seg + d) * 2048 + n0v + half;
    const u16* srcl = smem + c * 72 + half;
    #pragma unroll
    for (int e = 0; e < 4; ++e)
      *(uint4*)(dst + e * 8) = *(const uint4*)(srcl + e * 8);
  }
}

// ---------- kernel 1b: fallback, x fp32 reg-staged (writes Vt scattered) ----------
__global__ __launch_bounds__(256) void qkv_gemm_f32_kernel(
    const float* __restrict__ x, const u16* __restrict__ Wa,
    const u16* __restrict__ Wp, const u16* __restrict__ Wk,
    u16* __restrict__ Qb, u16* __restrict__ Kb, u16* __restrict__ Vt) {
  __shared__ u16 lA[128 * 64];
  __shared__ u16 lB[128 * 64];

  const int tid = threadIdx.x;
  const int w = tid >> 6, l = tid & 63;
  const int lr = l & 15, lg = l >> 4;
  const int wr = w >> 1, wc = w & 1;

  const int wg = blockIdx.x;
  const int xcd = wg & 7;
  const int q = wg >> 3;
  const int mtl = q / 12, nt = q % 12;
  const int mt = (xcd << 3) + mtl;

  const u16* W; int xoff, Kd, col0, dhs, seg;
  if (nt < 6)      { W = Wa; xoff = 0;    Kd = 2048; col0 = nt * 128;       dhs = 5; seg = 0;  }
  else if (nt < 9) { W = Wp; xoff = 2048; Kd = 1024; col0 = (nt - 6) * 128; dhs = 4; seg = 32; }
  else             { W = Wk; xoff = 3072; Kd = 1024; col0 = (nt - 9) * 128; dhs = 4; seg = 48; }
  const float qscale = (dhs == 5) ? 0.031880107f : 0.045084220f;

  const int m0 = mt * 128;
  f32x4 acc[4][4] = {};
  const int ubase = tid & ~63;

  const int nk = Kd >> 6;
  #pragma unroll 1
  for (int kt = 0; kt < nk; ++kt) {
    const int k0 = kt << 6;
    #pragma unroll
    for (int i = 0; i < 4; ++i) {
      const int ch = i * 256 + tid;
      const int row = ch >> 3, c8 = (ch & 7) << 3;
      const float* src = x + (size_t)(m0 + row) * 4096 + xoff + k0 + c8;
      const float4 a0 = *(const float4*)(src);
      const float4 a1 = *(const float4*)(src + 4);
      uint4 t;
      t.x = cvtpk(a0.x, a0.y); t.y = cvtpk(a0.z, a0.w);
      t.z = cvtpk(a1.x, a1.y); t.w = cvtpk(a1.z, a1.w);
      *(uint4*)(lA + (size_t)row * 64 + c8) = t;
    }
    #pragma unroll
    for (int i = 0; i < 4; ++i) {
      const int ch = i * 256 + tid;
      const int row = ch >> 3, c8 = (ch & 7) << 3;
      gl_lds16(W + (size_t)(col0 + row) * Kd + k0 + c8,
               lB + (size_t)(i * 256 + ubase) * 8);
    }
    __syncthreads();
    bf16x8 af[4][2], bfr[4][2];
    #pragma unroll
    for (int mi = 0; mi < 4; ++mi) {
      af[mi][0] = *(const bf16x8*)(lA + (wr * 64 + mi * 16 + lr) * 64 + lg * 8);
      af[mi][1] = *(const bf16x8*)(lA + (wr * 64 + mi * 16 + lr) * 64 + 32 + lg * 8);
    }
    #pragma unroll
    for (int ni = 0; ni < 4; ++ni) {
      bfr[ni][0] = *(const bf16x8*)(lB + (wc * 64 + ni * 16 + lr) * 64 + lg * 8);
      bfr[ni][1] = *(const bf16x8*)(lB + (wc * 64 + ni * 16 + lr) * 64 + 32 + lg * 8);
    }
    #pragma unroll
    for (int mi = 0; mi < 4; ++mi)
      #pragma unroll
      for (int ni = 0; ni < 4; ++ni) {
        acc[mi][ni] = __builtin_amdgcn_mfma_f32_16x16x32_bf16(af[mi][0], bfr[ni][0], acc[mi][ni], 0, 0, 0);
        acc[mi][ni] = __builtin_amdgcn_mfma_f32_16x16x32_bf16(af[mi][1], bfr[ni][1], acc[mi][ni], 0, 0, 0);
      }
    __syncthreads();
  }
  #pragma unroll
  for (int mi = 0; mi < 4; ++mi)
    #pragma unroll
    for (int ni = 0; ni < 4; ++ni) {
      const int c = col0 + wc * 64 + ni * 16 + lr;
      const int which = c >> (3 + dhs);
      const float f = (which == 0) ? qscale : 1.0f;
      const u32 r01 = cvtpk(acc[mi][ni][0] * f, acc[mi][ni][1] * f);
      const u32 r23 = cvtpk(acc[mi][ni][2] * f, acc[mi][ni][3] * f);
      const u16 bvv[4] = {(u16)r01, (u16)(r01 >> 16), (u16)r23, (u16)(r23 >> 16)};
      const int hd_mask = (8 << dhs) - 1;
      const int r = c & hd_mask;
      const int hh = r >> dhs;
      const int d = r & ((1 << dhs) - 1);
      #pragma unroll
      for (int j = 0; j < 4; ++j) {
        const int m = m0 + wr * 64 + mi * 16 + lg * 4 + j;
        const int bb = m >> 11, n = m & 2047;
        const size_t bhn = (size_t)(bb * 8 + hh) * 2048 + n;
        const u16 bv = bvv[j];
        if (which == 0)      Qb[bhn * 64 + seg + d] = bv;
        else if (which == 1) Kb[bhn * 64 + seg + d] = bv;
        else Vt[((size_t)(bb * 8 + hh) * 64 + seg + d) * 2048 + (n & ~63) + sigma_inv(n & 63)] = bv;
      }
    }
}

// ---------- kernel 2: fused 3-branch flash attention ----------
// QBLK=128 (512 thr). NEW: 4-buffer LDS (64 KB), stage-ahead-2, ONE barrier/tile.
// vmcnt(6) steady state = {mask,K,V} x 2 newest bodies in flight; stage(kt) proven
// complete. WAR separation = 1 barrier at buffer distance 4 (see derivation).
__global__ __launch_bounds__(512) void attn_kernel(
    const u16* __restrict__ Qb, const u16* __restrict__ Kb,
    const u16* __restrict__ Vt, const u32* __restrict__ mbits,
    u16* __restrict__ aout) {
  struct SMem {
    u16 sK[4][64 * 64];   // 4 x 8192 B
    u16 sV[4][64 * 64];   // 4 x 8192 B
  };
  __shared__ SMem sm;     // 65536 B

  const int tid = threadIdx.x;
  const int w = tid >> 6, l = tid & 63;
  const int lr = l & 15, lg = l >> 4;
  const int wg = blockIdx.x;            // 0..511
  const int xcd = wg & 7, rr0 = wg >> 3;
  const int bh = (xcd << 2) + (rr0 >> 4);   // each XCD: 4 bh x 16 qt
  const int qt = rr0 & 15;
  const int b = bh >> 3, h = bh & 7;
  const int q0 = qt << 7;               // 128 q-rows per block
  const size_t bhN = (size_t)bh * 2048;
  const int ubase = tid & ~63;

  const u16* qrow = Qb + (bhN + q0 + w * 16 + lr) * 64;
  const bf16x8 qf_a  = *(const bf16x8*)(qrow + lg * 8);
  const bf16x8 qf_pk = *(const bf16x8*)(qrow + 32 + lg * 8);
  bf16x8 zero8 = {};
  const bf16x8 qf_p = (lg < 2) ? qf_pk : zero8;
  const bf16x8 qf_k = (lg < 2) ? zero8 : qf_pk;

  const u32* mptr = mbits + ((size_t)b * 2048 + q0 + w * 16 + lr) * 64;

  const int sr = tid >> 3, swd = tid & 7;
  const u16* kp = Kb + (bhN + sr) * 64 + (swd ^ (sr & 7)) * 8;          // + kt*4096
  const u16* vp = Vt + ((size_t)bh * 64 + sr) * 2048 + (swd ^ (sr & 7)) * 8;  // + kt*64
  u16* dK[4] = { &sm.sK[0][0] + ubase * 8, &sm.sK[1][0] + ubase * 8,
                 &sm.sK[2][0] + ubase * 8, &sm.sK[3][0] + ubase * 8 };
  u16* dV[4] = { &sm.sV[0][0] + ubase * 8, &sm.sV[1][0] + ubase * 8,
                 &sm.sV[2][0] + ubase * 8, &sm.sV[3][0] + ubase * 8 };

  // prologue: stage tiles 0,1 + masks 0,1
  gl_lds16(kp, dK[0]);               gl_lds16(vp, dV[0]);
  gl_lds16(kp + 4096, dK[1]);        gl_lds16(vp + 64, dV[1]);
  uint2 m0 = *(const uint2*)(mptr);
  uint2 m1 = *(const uint2*)(mptr + 2);
  uint2 m2, m3;

  bf16x8 vones;
  #pragma unroll
  for (int e = 0; e < 8; ++e) vones[e] = __builtin_bit_cast(__bf16, (u16)0x3F80);

  f32x4 oacc[3][4] = {};
  f32x4 osum[3] = {};
  const int c4 = (lg << 2);
  const int xk = lr & 7;

  auto body = [&](int kt, int cur, int sb, bool st2, int wc, uint2 mkv, uint2* mknext) {
    if (st2) {
      *mknext = *(const uint2*)(mptr + ((kt + 2) << 1));   // mask(kt+2)
      gl_lds16(kp + (size_t)(kt + 2) * 4096, dK[sb]);
      gl_lds16(vp + (size_t)(kt + 2) * 64, dV[sb]);
    }
    if (wc == 6)      asm volatile("s_waitcnt vmcnt(6)" ::: "memory");
    else if (wc == 3) asm volatile("s_waitcnt vmcnt(3)" ::: "memory");
    else              asm volatile("s_waitcnt vmcnt(0)" ::: "memory");
    __builtin_amdgcn_sched_barrier(0);
    __builtin_amdgcn_s_barrier();   // single barrier per tile

    u32 msk[4][2];
    #pragma unroll
    for (int j = 0; j < 4; ++j) {
      const int c = c4 + j;
      const u32 u0 = (mkv.x >> c) & 0x00010001u;
      const u32 u1 = (mkv.y >> c) & 0x00010001u;
      msk[j][0] = (u0 << 16) - u0;
      msk[j][1] = (u1 << 16) - u1;
    }

    bf16x8 vb[4][2];
    #pragma unroll
    for (int ct = 0; ct < 4; ++ct) {
      const u16* vrow = &sm.sV[cur][0] + (ct * 16 + lr) * 64;
      vb[ct][0] = *(const bf16x8*)(vrow + (lg ^ xk) * 8);
      vb[ct][1] = *(const bf16x8*)(vrow + ((lg + 4) ^ xk) * 8);
    }

    const f32x4 fz = {0.f, 0.f, 0.f, 0.f};
    auto softpv = [&](f32x4 (&sacc)[4], int s) {
      uint4 pw0, pw1;
      u32* w0 = (u32*)&pw0; u32* w1 = (u32*)&pw1;
      #pragma unroll
      for (int j = 0; j < 4; ++j) {
        w0[j] = cvtpk(rexp2(sacc[0][j]), rexp2(sacc[1][j])) & msk[j][0];
        w1[j] = cvtpk(rexp2(sacc[2][j]), rexp2(sacc[3][j])) & msk[j][1];
      }
      const bf16x8 pa0 = __builtin_bit_cast(bf16x8, pw0);
      const bf16x8 pa1 = __builtin_bit_cast(bf16x8, pw1);
      __builtin_amdgcn_s_setprio(1);
      #pragma unroll
      for (int ct = 0; ct < 4; ++ct) {
        oacc[s][ct] = __builtin_amdgcn_mfma_f32_16x16x32_bf16(pa0, vb[ct][0], oacc[s][ct], 0, 0, 0);
        oacc[s][ct] = __builtin_amdgcn_mfma_f32_16x16x32_bf16(pa1, vb[ct][1], oacc[s][ct], 0, 0, 0);
      }
      osum[s] = __builtin_amdgcn_mfma_f32_16x16x32_bf16(pa0, vones, osum[s], 0, 0, 0);
      osum[s] = __builtin_amdgcn_mfma_f32_16x16x32_bf16(pa1, vones, osum[s], 0, 0, 0);
      __builtin_amdgcn_s_setprio(0);
    };

    {  // segment a
      f32x4 sacc[4];
      __builtin_amdgcn_s_setprio(1);
      #pragma unroll
      for (int t = 0; t < 4; ++t) {
        const bf16x8 kf = *(const bf16x8*)(&sm.sK[cur][0] + (t * 16 + lr) * 64 + ((lg ^ xk) * 8));
        sacc[t] = __builtin_amdgcn_mfma_f32_16x16x32_bf16(kf, qf_a, fz, 0, 0, 0);
      }
      __builtin_amdgcn_s_setprio(0);
      softpv(sacc, 0);
    }
    {  // segment p
      f32x4 sacc[4];
      __builtin_amdgcn_s_setprio(1);
      #pragma unroll
      for (int t = 0; t < 4; ++t) {
        const bf16x8 kf = *(const bf16x8*)(&sm.sK[cur][0] + (t * 16 + lr) * 64 + (((lg + 4) ^ xk) * 8));
        sacc[t] = __builtin_amdgcn_mfma_f32_16x16x32_bf16(kf, qf_p, fz, 0, 0, 0);
      }
      __builtin_amdgcn_s_setprio(0);
      softpv(sacc, 1);
    }
    {  // segment k
      f32x4 sacc[4];
      __builtin_amdgcn_s_setprio(1);
      #pragma unroll
      for (int t = 0; t < 4; ++t) {
        const bf16x8 kf = *(const bf16x8*)(&sm.sK[cur][0] + (t * 16 + lr) * 64 + (((lg + 4) ^ xk) * 8));
        sacc[t] = __builtin_amdgcn_mfma_f32_16x16x32_bf16(kf, qf_k, fz, 0, 0, 0);
      }
      __builtin_amdgcn_s_setprio(0);
      softpv(sacc, 2);
    }
  };

  #pragma unroll 1
  for (int it = 0; it < 8; ++it) {
    const int kt0 = it * 4;
    const bool l7 = (it < 7);
    body(kt0 + 0, 0, 2, true, (kt0 == 0) ? 3 : 6, m0, &m2);
    body(kt0 + 1, 1, 3, true, 6, m1, &m3);
    body(kt0 + 2, 2, 0, l7, l7 ? 6 : 3, m2, &m0);
    body(kt0 + 3, 3, 1, l7, l7 ? 6 : 0, m3, &m1);
  }

  float linv[3][4];
  #pragma unroll
  for (int s = 0; s < 3; ++s)
    #pragma unroll
    for (int j = 0; j < 4; ++j)
      linv[s][j] = 1.0f / (3.0f * osum[s][j] + 1e-30f);

  #pragma unroll
  for (int ct = 0; ct < 4; ++ct) {
    float vj[4];
    #pragma unroll
    for (int j = 0; j < 4; ++j)
      vj[j] = oacc[0][ct][j] * linv[0][j]
            + oacc[1][ct][j] * linv[1][j]
            + oacc[2][ct][j] * linv[2][j];
    const u32 r01 = cvtpk(vj[0], vj[1]);
    const u32 r23 = cvtpk(vj[2], vj[3]);
    const u16 bvv[4] = {(u16)r01, (u16)(r01 >> 16), (u16)r23, (u16)(r23 >> 16)};
    #pragma unroll
    for (int j = 0; j < 4; ++j) {
      const int row = q0 + w * 16 + lg * 4 + j;
      const int col = h * 64 + ct * 16 + lr;
      aout[((size_t)b * 2048 + row) * 512 + col] = bvv[j];
    }
  }
}

// ---------- kernel 3: output projection, M64xN64 tiles ----------
__global__ __launch_bounds__(256) void out_gemm_kernel(
    const u16* __restrict__ A, const u16* __restrict__ Wo,
    const float* __restrict__ bias, float* __restrict__ out) {
  __shared__ u16 lA[64 * 64];
  __shared__ u16 lB[64 * 64];

  const int tid = threadIdx.x;
  const int w = tid >> 6, l = tid & 63;
  const int lr = l & 15, lg = l >> 4;

  const int wg = blockIdx.x;
  const int xcd = wg & 7;
  const int q = wg >> 3;
  const int mt = (xcd << 4) + (q >> 3);
  const int nt = q & 7;
  const int col0 = nt * 64;
  const int m0 = mt * 64;
  f32x4 acc[4] = {};
  const int ubase = tid & ~63;

  #pragma unroll 1
  for (int kt = 0; kt < 8; ++kt) {
    const int k0 = kt << 6;
    #pragma unroll
    for (int i = 0; i < 2; ++i) {
      const int ch = i * 256 + tid;
      const int row = ch >> 3, c8 = (ch & 7) << 3;
      gl_lds16(A + (size_t)(m0 + row) * 512 + k0 + c8, lA + (size_t)(i * 256 + ubase) * 8);
    }
    #pragma unroll
    for (int i = 0; i < 2; ++i) {
      const int ch = i * 256 + tid;
      const int row = ch >> 3, c8 = (ch & 7) << 3;
      gl_lds16(Wo + (size_t)(col0 + row) * 512 + k0 + c8, lB + (size_t)(i * 256 + ubase) * 8);
    }
    __syncthreads();
    bf16x8 af[4][2], bfr[2];
    #pragma unroll
    for (int mi = 0; mi < 4; ++mi) {
      af[mi][0] = *(const bf16x8*)(lA + (mi * 16 + lr) * 64 + lg * 8);
      af[mi][1] = *(const bf16x8*)(lA + (mi * 16 + lr) * 64 + 32 + lg * 8);
    }
    bfr[0] = *(const bf16x8*)(lB + (w * 16 + lr) * 64 + lg * 8);
    bfr[1] = *(const bf16x8*)(lB + (w * 16 + lr) * 64 + 32 + lg * 8);
    #pragma unroll
    for (int mi = 0; mi < 4; ++mi) {
      acc[mi] = __builtin_amdgcn_mfma_f32_16x16x32_bf16(af[mi][0], bfr[0], acc[mi], 0, 0, 0);
      acc[mi] = __builtin_amdgcn_mfma_f32_16x16x32_bf16(af[mi][1], bfr[1], acc[mi], 0, 0, 0);
    }
    __syncthreads();
  }

  const int c = col0 + w * 16 + lr;
  const float bv = bias[c];
  #pragma unroll
  for (int mi = 0; mi < 4; ++mi)
    #pragma unroll
    for (int j = 0; j < 4; ++j) {
      const int m = m0 + mi * 16 + lg * 4 + j;
      out[(size_t)m * 512 + c] = acc[mi][j] + bv;
    }
}

// ---------- launcher ----------
extern "C" void kernel_launch(void* const* d_in, const int* in_sizes, int n_in,
                              void* d_out, int out_size, void* d_ws, size_t ws_size,
                              hipStream_t stream) {
  const float* x    = (const float*)d_in[0];
  const float* Wa   = (const float*)d_in[1];
  const float* Wp   = (const float*)d_in[2];
  const float* Wk   = (const float*)d_in[3];
  const float* Wo   = (const float*)d_in[4];
  const float* bo   = (const float*)d_in[5];
  const int* mask   = (const int*)d_in[6];
  float* out = (float*)d_out;

  char* ws = (char*)d_ws;
  u16* Wab = (u16*)ws;                    //  3,145,728 B
  u16* Wpb = (u16*)(ws + 3145728);        //    786,432 B
  u16* Wkb = (u16*)(ws + 3932160);        //    786,432 B
  u16* Wob = (u16*)(ws + 4718592);        //    524,288 B
  u16* Qb  = (u16*)(ws + 5242880);        //  8,388,608 B  [B,H,N,64] bf16
  u16* Kb  = (u16*)(ws + 13631488);       //  8,388,608 B  [B,H,N,64] bf16
  u16* Vt  = (u16*)(ws + 22020096);       //  8,388,608 B  [B*H,64,2048] bf16 (sigma-perm)
  u64* Mb  = (u64*)(ws + 30408704);       //  2,097,152 B  bitmask
  u16* Ao  = (u16*)(ws + 32505856);       //  8,388,608 B  attn out [B,N,512] bf16
  u16* xb  = (u16*)(ws + 40894464);       // 67,108,864 B  x bf16 (optional)

  const bool use_xb = ws_size >= (size_t)40894464 + 67108864;
  const int xblocks = use_xb ? 8192 : 0;

  prep_kernel<<<xblocks + 2560 + 1024, 256, 0, stream>>>(
      x, xb, Wa, Wp, Wk, Wo, Wab, Wpb, Wkb, Wob, mask, (u64*)Mb, xblocks);
  if (use_xb) {
    qkv_gemm_kernel<<<1536, 256, 0, stream>>>(xb, Wab, Wpb, Wkb, Qb, Kb, Vt);
  } else {
    qkv_gemm_f32_kernel<<<768, 256, 0, stream>>>(x, Wab, Wpb, Wkb, Qb, Kb, Vt);
  }
  attn_kernel<<<512, 512, 0, stream>>>(Qb, Kb, Vt, (const u32*)Mb, Ao);
  out_gemm_kernel<<<1024, 256, 0, stream>>>(Ao, Wob, bo, out);
}

// Round 20
// 254.012 us; speedup vs baseline: 1.1414x; 1.0321x over previous
//
#include <hip/hip_runtime.h>
#include <hip/hip_bf16.h>

typedef __attribute__((ext_vector_type(8))) __bf16 bf16x8;
typedef __attribute__((ext_vector_type(4))) float f32x4;
typedef unsigned short u16;
typedef unsigned int u32;
typedef unsigned long long u64;

// ---------- helpers ----------
__device__ __forceinline__ u32 cvtpk(float lo, float hi) {  // {bf16(lo) | bf16(hi)<<16}
  u32 r;
  asm("v_cvt_pk_bf16_f32 %0, %1, %2" : "=v"(r) : "v"(lo), "v"(hi));
  return r;
}
__device__ __forceinline__ float rexp2(float x) {           // raw v_exp_f32 (2^x)
  float r;
  asm("v_exp_f32 %0, %1" : "=v"(r) : "v"(x));
  return r;
}
__device__ __forceinline__ void gl_lds16(const void* g, void* l) {
  __builtin_amdgcn_global_load_lds((const __attribute__((address_space(1))) void*)g,
                                   (__attribute__((address_space(3))) void*)l, 16, 0, 0);
}
__device__ __forceinline__ int sigma_inv(int n) {           // V key permutation (64-block)
  return ((n >> 5) << 5) | (((n & 15) >> 2) << 3) | ((n & 3) << 1) | ((n >> 4) & 1);
}

// ---------- kernel P: fused prep (xcvt | wcvt | maskbits) ----------
// xcvt now PERFECTLY coalesced: per load instr, lane stride 16B (1KB/wave);
// per store instr, lane stride 8B (512B/wave).
__global__ __launch_bounds__(256) void prep_kernel(
    const float* __restrict__ x, u16* __restrict__ xb,
    const float* __restrict__ Wa, const float* __restrict__ Wp,
    const float* __restrict__ Wk, const float* __restrict__ Wo,
    u16* __restrict__ Wab, u16* __restrict__ Wpb,
    u16* __restrict__ Wkb, u16* __restrict__ Wob,
    const int* __restrict__ mask, u64* __restrict__ bits, int xblocks) {
  int bid = blockIdx.x;
  if (bid < xblocks) {                       // ---- xcvt (4096 floats/block) ----
    const int base = bid * 4096 + threadIdx.x * 4;
    #pragma unroll
    for (int c = 0; c < 4; ++c) {
      const float4 a = *(const float4*)(x + base + c * 1024);
      *(uint2*)(xb + base + c * 1024) = make_uint2(cvtpk(a.x, a.y), cvtpk(a.z, a.w));
    }
    return;
  }
  bid -= xblocks;
  if (bid < 2560) {                          // ---- wcvt ----
    const float* s; u16* d; int base;
    if (bid < 1536)      { s = Wa; d = Wab; base = bid; }
    else if (bid < 1920) { s = Wp; d = Wpb; base = bid - 1536; }
    else if (bid < 2304) { s = Wk; d = Wkb; base = bid - 1920; }
    else                 { s = Wo; d = Wob; base = bid - 2304; }
    const int idx = (base * 256 + threadIdx.x) * 4;
    const float4 v = *(const float4*)(s + idx);
    *(uint2*)(d + idx) = make_uint2(cvtpk(v.x, v.y), cvtpk(v.z, v.w));
    return;
  }
  bid -= 2560;                               // ---- maskbits ----
  const int lane = threadIdx.x & 63;
  const long long gw = (long long)bid * 4 + (threadIdx.x >> 6);
  const long long nwaves = 1024LL * 4;
  const long long nwords = 16777216LL / 64;
  for (long long i = gw; i < nwords; i += nwaves) {
    const int m = mask[i * 64 + lane];
    const u64 bal = __ballot(m > 0);
    if (lane == 0) bits[i] = bal;
  }
}

// ---------- QKV Q/K store ----------
__device__ __forceinline__ void qk_store(
    float v0, float v1, float v2, float v3, int m_base, int c,
    int dhs, int seg, float fs,
    u16* __restrict__ Qb, u16* __restrict__ Kb) {
  const int which = c >> (3 + dhs);
  const float f = (which == 0) ? fs : 1.0f;
  const u32 r01 = cvtpk(v0 * f, v1 * f);
  const u32 r23 = cvtpk(v2 * f, v3 * f);
  const u16 bvv[4] = {(u16)r01, (u16)(r01 >> 16), (u16)r23, (u16)(r23 >> 16)};
  const int hd_mask = (8 << dhs) - 1;
  const int r = c & hd_mask;
  const int hh = r >> dhs;
  const int d = r & ((1 << dhs) - 1);
  #pragma unroll
  for (int j = 0; j < 4; ++j) {
    const int m = m_base + j;
    const int bb = m >> 11, n = m & 2047;
    const size_t bhn = (size_t)(bb * 8 + hh) * 2048 + n;
    const u16 bv = bvv[j];
    if (which == 0) Qb[bhn * 64 + seg + d] = bv;
    else            Kb[bhn * 64 + seg + d] = bv;
  }
}

// ---------- kernel 1a: QKV GEMM bf16, M64xN128 tiles ----------
// V-producing block types (nt in {4,5,8,11}) are PURE-V: epilogue does an LDS
// sigma-transpose and writes Vt[bh*64+d][n] directly.
__global__ __launch_bounds__(256) void qkv_gemm_kernel(
    const u16* __restrict__ xb, const u16* __restrict__ Wa,
    const u16* __restrict__ Wp, const u16* __restrict__ Wk,
    u16* __restrict__ Qb, u16* __restrict__ Kb, u16* __restrict__ Vt) {
  __shared__ u16 smem[64 * 64 + 128 * 64];   // 24 KB; V epilogue reuses as lt[128][72]
  u16* lA = smem;
  u16* lB = smem + 64 * 64;

  const int tid = threadIdx.x;
  const int w = tid >> 6, l = tid & 63;
  const int lr = l & 15, lg = l >> 4;

  const int wg = blockIdx.x;
  const int xcd = wg & 7;
  const int q = wg >> 3;
  const int mtl = q / 12, nt = q % 12;
  const int mt = (xcd << 4) + mtl;

  const u16* W; int xoff, Kd, col0, dhs, seg;
  if (nt < 6)      { W = Wa; xoff = 0;    Kd = 2048; col0 = nt * 128;       dhs = 5; seg = 0;  }
  else if (nt < 9) { W = Wp; xoff = 2048; Kd = 1024; col0 = (nt - 6) * 128; dhs = 4; seg = 32; }
  else             { W = Wk; xoff = 3072; Kd = 1024; col0 = (nt - 9) * 128; dhs = 4; seg = 48; }
  const float qscale = (dhs == 5) ? 0.031880107f : 0.045084220f;  // D^-0.5 * log2(e)
  const bool isV = (nt == 4) | (nt == 5) | (nt == 8) | (nt == 11);

  const int m0 = mt * 64;
  f32x4 acc[4][2] = {};
  const int ubase = tid & ~63;

  const int nk = Kd >> 6;
  #pragma unroll 1
  for (int kt = 0; kt < nk; ++kt) {
    const int k0 = kt << 6;
    #pragma unroll
    for (int i = 0; i < 2; ++i) {
      const int ch = i * 256 + tid;
      const int row = ch >> 3, c8 = (ch & 7) << 3;
      gl_lds16(xb + (size_t)(m0 + row) * 4096 + xoff + k0 + c8,
               lA + (size_t)(i * 256 + ubase) * 8);
    }
    #pragma unroll
    for (int i = 0; i < 4; ++i) {
      const int ch = i * 256 + tid;
      const int row = ch >> 3, c8 = (ch & 7) << 3;
      gl_lds16(W + (size_t)(col0 + row) * Kd + k0 + c8,
               lB + (size_t)(i * 256 + ubase) * 8);
    }
    __syncthreads();
    bf16x8 af[4][2], bfr[2][2];
    #pragma unroll
    for (int mi = 0; mi < 4; ++mi) {
      af[mi][0] = *(const bf16x8*)(lA + (mi * 16 + lr) * 64 + lg * 8);
      af[mi][1] = *(const bf16x8*)(lA + (mi * 16 + lr) * 64 + 32 + lg * 8);
    }
    #pragma unroll
    for (int ni = 0; ni < 2; ++ni) {
      bfr[ni][0] = *(const bf16x8*)(lB + (w * 32 + ni * 16 + lr) * 64 + lg * 8);
      bfr[ni][1] = *(const bf16x8*)(lB + (w * 32 + ni * 16 + lr) * 64 + 32 + lg * 8);
    }
    #pragma unroll
    for (int mi = 0; mi < 4; ++mi)
      #pragma unroll
      for (int ni = 0; ni < 2; ++ni) {
        acc[mi][ni] = __builtin_amdgcn_mfma_f32_16x16x32_bf16(af[mi][0], bfr[ni][0], acc[mi][ni], 0, 0, 0);
        acc[mi][ni] = __builtin_amdgcn_mfma_f32_16x16x32_bf16(af[mi][1], bfr[ni][1], acc[mi][ni], 0, 0, 0);
      }
    __syncthreads();
  }

  if (!isV) {
    #pragma unroll
    for (int mi = 0; mi < 4; ++mi)
      #pragma unroll
      for (int ni = 0; ni < 2; ++ni)
        qk_store(acc[mi][ni][0], acc[mi][ni][1], acc[mi][ni][2], acc[mi][ni][3],
                 m0 + mi * 16 + lg * 4, col0 + w * 32 + ni * 16 + lr,
                 dhs, seg, qscale, Qb, Kb);
  } else {
    // sigma-transpose via LDS: lt[c 0..127][pos 0..63] stride 72
    #pragma unroll
    for (int mi = 0; mi < 4; ++mi)
      #pragma unroll
      for (int ni = 0; ni < 2; ++ni) {
        const u32 r01 = cvtpk(acc[mi][ni][0], acc[mi][ni][1]);
        const u32 r23 = cvtpk(acc[mi][ni][2], acc[mi][ni][3]);
        const u16 bvv[4] = {(u16)r01, (u16)(r01 >> 16), (u16)r23, (u16)(r23 >> 16)};
        const int cl = w * 32 + ni * 16 + lr;
        #pragma unroll
        for (int j = 0; j < 4; ++j) {
          const int n = mi * 16 + lg * 4 + j;
          smem[cl * 72 + sigma_inv(n)] = bvv[j];
        }
      }
    __syncthreads();
    const int c = tid >> 1, half = (tid & 1) << 5;
    const int hd_mask = (8 << dhs) - 1;
    const int r = (col0 + c) & hd_mask;
    const int hh = r >> dhs, d = r & ((1 << dhs) - 1);
    const int bb = m0 >> 11, n0v = m0 & 2047;
    u16* dst = Vt + ((size_t)(bb * 8 + hh) * 64 + seg + d) * 2048 + n0v + half;
    const u16* srcl = smem + c * 72 + half;
    #pragma unroll
    for (int e = 0; e < 4; ++e)
      *(uint4*)(dst + e * 8) = *(const uint4*)(srcl + e * 8);
  }
}

// ---------- kernel 1b: fallback, x fp32 reg-staged (writes Vt scattered) ----------
__global__ __launch_bounds__(256) void qkv_gemm_f32_kernel(
    const float* __restrict__ x, const u16* __restrict__ Wa,
    const u16* __restrict__ Wp, const u16* __restrict__ Wk,
    u16* __restrict__ Qb, u16* __restrict__ Kb, u16* __restrict__ Vt) {
  __shared__ u16 lA[128 * 64];
  __shared__ u16 lB[128 * 64];

  const int tid = threadIdx.x;
  const int w = tid >> 6, l = tid & 63;
  const int lr = l & 15, lg = l >> 4;
  const int wr = w >> 1, wc = w & 1;

  const int wg = blockIdx.x;
  const int xcd = wg & 7;
  const int q = wg >> 3;
  const int mtl = q / 12, nt = q % 12;
  const int mt = (xcd << 3) + mtl;

  const u16* W; int xoff, Kd, col0, dhs, seg;
  if (nt < 6)      { W = Wa; xoff = 0;    Kd = 2048; col0 = nt * 128;       dhs = 5; seg = 0;  }
  else if (nt < 9) { W = Wp; xoff = 2048; Kd = 1024; col0 = (nt - 6) * 128; dhs = 4; seg = 32; }
  else             { W = Wk; xoff = 3072; Kd = 1024; col0 = (nt - 9) * 128; dhs = 4; seg = 48; }
  const float qscale = (dhs == 5) ? 0.031880107f : 0.045084220f;

  const int m0 = mt * 128;
  f32x4 acc[4][4] = {};
  const int ubase = tid & ~63;

  const int nk = Kd >> 6;
  #pragma unroll 1
  for (int kt = 0; kt < nk; ++kt) {
    const int k0 = kt << 6;
    #pragma unroll
    for (int i = 0; i < 4; ++i) {
      const int ch = i * 256 + tid;
      const int row = ch >> 3, c8 = (ch & 7) << 3;
      const float* src = x + (size_t)(m0 + row) * 4096 + xoff + k0 + c8;
      const float4 a0 = *(const float4*)(src);
      const float4 a1 = *(const float4*)(src + 4);
      uint4 t;
      t.x = cvtpk(a0.x, a0.y); t.y = cvtpk(a0.z, a0.w);
      t.z = cvtpk(a1.x, a1.y); t.w = cvtpk(a1.z, a1.w);
      *(uint4*)(lA + (size_t)row * 64 + c8) = t;
    }
    #pragma unroll
    for (int i = 0; i < 4; ++i) {
      const int ch = i * 256 + tid;
      const int row = ch >> 3, c8 = (ch & 7) << 3;
      gl_lds16(W + (size_t)(col0 + row) * Kd + k0 + c8,
               lB + (size_t)(i * 256 + ubase) * 8);
    }
    __syncthreads();
    bf16x8 af[4][2], bfr[4][2];
    #pragma unroll
    for (int mi = 0; mi < 4; ++mi) {
      af[mi][0] = *(const bf16x8*)(lA + (wr * 64 + mi * 16 + lr) * 64 + lg * 8);
      af[mi][1] = *(const bf16x8*)(lA + (wr * 64 + mi * 16 + lr) * 64 + 32 + lg * 8);
    }
    #pragma unroll
    for (int ni = 0; ni < 4; ++ni) {
      bfr[ni][0] = *(const bf16x8*)(lB + (wc * 64 + ni * 16 + lr) * 64 + lg * 8);
      bfr[ni][1] = *(const bf16x8*)(lB + (wc * 64 + ni * 16 + lr) * 64 + 32 + lg * 8);
    }
    #pragma unroll
    for (int mi = 0; mi < 4; ++mi)
      #pragma unroll
      for (int ni = 0; ni < 4; ++ni) {
        acc[mi][ni] = __builtin_amdgcn_mfma_f32_16x16x32_bf16(af[mi][0], bfr[ni][0], acc[mi][ni], 0, 0, 0);
        acc[mi][ni] = __builtin_amdgcn_mfma_f32_16x16x32_bf16(af[mi][1], bfr[ni][1], acc[mi][ni], 0, 0, 0);
      }
    __syncthreads();
  }
  #pragma unroll
  for (int mi = 0; mi < 4; ++mi)
    #pragma unroll
    for (int ni = 0; ni < 4; ++ni) {
      const int c = col0 + wc * 64 + ni * 16 + lr;
      const int which = c >> (3 + dhs);
      const float f = (which == 0) ? qscale : 1.0f;
      const u32 r01 = cvtpk(acc[mi][ni][0] * f, acc[mi][ni][1] * f);
      const u32 r23 = cvtpk(acc[mi][ni][2] * f, acc[mi][ni][3] * f);
      const u16 bvv[4] = {(u16)r01, (u16)(r01 >> 16), (u16)r23, (u16)(r23 >> 16)};
      const int hd_mask = (8 << dhs) - 1;
      const int r = c & hd_mask;
      const int hh = r >> dhs;
      const int d = r & ((1 << dhs) - 1);
      #pragma unroll
      for (int j = 0; j < 4; ++j) {
        const int m = m0 + wr * 64 + mi * 16 + lg * 4 + j;
        const int bb = m >> 11, n = m & 2047;
        const size_t bhn = (size_t)(bb * 8 + hh) * 2048 + n;
        const u16 bv = bvv[j];
        if (which == 0)      Qb[bhn * 64 + seg + d] = bv;
        else if (which == 1) Kb[bhn * 64 + seg + d] = bv;
        else Vt[((size_t)(bb * 8 + hh) * 64 + seg + d) * 2048 + (n & ~63) + sigma_inv(n & 63)] = bv;
      }
    }
}

// ---------- kernel 2: fused 3-branch flash attention ----------
// QBLK=128 (512 thr). 4-buffer LDS (64 KB), stage-ahead-2, ONE barrier/tile.
// vmcnt(6) steady state = {mask,K,V} x 2 newest bodies in flight.
__global__ __launch_bounds__(512) void attn_kernel(
    const u16* __restrict__ Qb, const u16* __restrict__ Kb,
    const u16* __restrict__ Vt, const u32* __restrict__ mbits,
    u16* __restrict__ aout) {
  struct SMem {
    u16 sK[4][64 * 64];   // 4 x 8192 B
    u16 sV[4][64 * 64];   // 4 x 8192 B
  };
  __shared__ SMem sm;     // 65536 B

  const int tid = threadIdx.x;
  const int w = tid >> 6, l = tid & 63;
  const int lr = l & 15, lg = l >> 4;
  const int wg = blockIdx.x;            // 0..511
  const int xcd = wg & 7, rr0 = wg >> 3;
  const int bh = (xcd << 2) + (rr0 >> 4);   // each XCD: 4 bh x 16 qt
  const int qt = rr0 & 15;
  const int b = bh >> 3, h = bh & 7;
  const int q0 = qt << 7;               // 128 q-rows per block
  const size_t bhN = (size_t)bh * 2048;
  const int ubase = tid & ~63;

  const u16* qrow = Qb + (bhN + q0 + w * 16 + lr) * 64;
  const bf16x8 qf_a  = *(const bf16x8*)(qrow + lg * 8);
  const bf16x8 qf_pk = *(const bf16x8*)(qrow + 32 + lg * 8);
  bf16x8 zero8 = {};
  const bf16x8 qf_p = (lg < 2) ? qf_pk : zero8;
  const bf16x8 qf_k = (lg < 2) ? zero8 : qf_pk;

  const u32* mptr = mbits + ((size_t)b * 2048 + q0 + w * 16 + lr) * 64;

  const int sr = tid >> 3, swd = tid & 7;
  const u16* kp = Kb + (bhN + sr) * 64 + (swd ^ (sr & 7)) * 8;          // + kt*4096
  const u16* vp = Vt + ((size_t)bh * 64 + sr) * 2048 + (swd ^ (sr & 7)) * 8;  // + kt*64
  u16* dK[4] = { &sm.sK[0][0] + ubase * 8, &sm.sK[1][0] + ubase * 8,
                 &sm.sK[2][0] + ubase * 8, &sm.sK[3][0] + ubase * 8 };
  u16* dV[4] = { &sm.sV[0][0] + ubase * 8, &sm.sV[1][0] + ubase * 8,
                 &sm.sV[2][0] + ubase * 8, &sm.sV[3][0] + ubase * 8 };

  // prologue: stage tiles 0,1 + masks 0,1
  gl_lds16(kp, dK[0]);               gl_lds16(vp, dV[0]);
  gl_lds16(kp + 4096, dK[1]);        gl_lds16(vp + 64, dV[1]);
  uint2 m0 = *(const uint2*)(mptr);
  uint2 m1 = *(const uint2*)(mptr + 2);
  uint2 m2, m3;

  bf16x8 vones;
  #pragma unroll
  for (int e = 0; e < 8; ++e) vones[e] = __builtin_bit_cast(__bf16, (u16)0x3F80);

  f32x4 oacc[3][4] = {};
  f32x4 osum[3] = {};
  const int c4 = (lg << 2);
  const int xk = lr & 7;

  auto body = [&](int kt, int cur, int sb, bool st2, int wc, uint2 mkv, uint2* mknext) {
    if (st2) {
      *mknext = *(const uint2*)(mptr + ((kt + 2) << 1));   // mask(kt+2)
      gl_lds16(kp + (size_t)(kt + 2) * 4096, dK[sb]);
      gl_lds16(vp + (size_t)(kt + 2) * 64, dV[sb]);
    }
    if (wc == 6)      asm volatile("s_waitcnt vmcnt(6)" ::: "memory");
    else if (wc == 3) asm volatile("s_waitcnt vmcnt(3)" ::: "memory");
    else              asm volatile("s_waitcnt vmcnt(0)" ::: "memory");
    __builtin_amdgcn_sched_barrier(0);
    __builtin_amdgcn_s_barrier();   // single barrier per tile

    u32 msk[4][2];
    #pragma unroll
    for (int j = 0; j < 4; ++j) {
      const int c = c4 + j;
      const u32 u0 = (mkv.x >> c) & 0x00010001u;
      const u32 u1 = (mkv.y >> c) & 0x00010001u;
      msk[j][0] = (u0 << 16) - u0;
      msk[j][1] = (u1 << 16) - u1;
    }

    bf16x8 vb[4][2];
    #pragma unroll
    for (int ct = 0; ct < 4; ++ct) {
      const u16* vrow = &sm.sV[cur][0] + (ct * 16 + lr) * 64;
      vb[ct][0] = *(const bf16x8*)(vrow + (lg ^ xk) * 8);
      vb[ct][1] = *(const bf16x8*)(vrow + ((lg + 4) ^ xk) * 8);
    }

    const f32x4 fz = {0.f, 0.f, 0.f, 0.f};
    auto softpv = [&](f32x4 (&sacc)[4], int s) {
      uint4 pw0, pw1;
      u32* w0 = (u32*)&pw0; u32* w1 = (u32*)&pw1;
      #pragma unroll
      for (int j = 0; j < 4; ++j) {
        w0[j] = cvtpk(rexp2(sacc[0][j]), rexp2(sacc[1][j])) & msk[j][0];
        w1[j] = cvtpk(rexp2(sacc[2][j]), rexp2(sacc[3][j])) & msk[j][1];
      }
      const bf16x8 pa0 = __builtin_bit_cast(bf16x8, pw0);
      const bf16x8 pa1 = __builtin_bit_cast(bf16x8, pw1);
      __builtin_amdgcn_s_setprio(1);
      #pragma unroll
      for (int ct = 0; ct < 4; ++ct) {
        oacc[s][ct] = __builtin_amdgcn_mfma_f32_16x16x32_bf16(pa0, vb[ct][0], oacc[s][ct], 0, 0, 0);
        oacc[s][ct] = __builtin_amdgcn_mfma_f32_16x16x32_bf16(pa1, vb[ct][1], oacc[s][ct], 0, 0, 0);
      }
      osum[s] = __builtin_amdgcn_mfma_f32_16x16x32_bf16(pa0, vones, osum[s], 0, 0, 0);
      osum[s] = __builtin_amdgcn_mfma_f32_16x16x32_bf16(pa1, vones, osum[s], 0, 0, 0);
      __builtin_amdgcn_s_setprio(0);
    };

    {  // segment a
      f32x4 sacc[4];
      __builtin_amdgcn_s_setprio(1);
      #pragma unroll
      for (int t = 0; t < 4; ++t) {
        const bf16x8 kf = *(const bf16x8*)(&sm.sK[cur][0] + (t * 16 + lr) * 64 + ((lg ^ xk) * 8));
        sacc[t] = __builtin_amdgcn_mfma_f32_16x16x32_bf16(kf, qf_a, fz, 0, 0, 0);
      }
      __builtin_amdgcn_s_setprio(0);
      softpv(sacc, 0);
    }
    {  // segment p
      f32x4 sacc[4];
      __builtin_amdgcn_s_setprio(1);
      #pragma unroll
      for (int t = 0; t < 4; ++t) {
        const bf16x8 kf = *(const bf16x8*)(&sm.sK[cur][0] + (t * 16 + lr) * 64 + (((lg + 4) ^ xk) * 8));
        sacc[t] = __builtin_amdgcn_mfma_f32_16x16x32_bf16(kf, qf_p, fz, 0, 0, 0);
      }
      __builtin_amdgcn_s_setprio(0);
      softpv(sacc, 1);
    }
    {  // segment k
      f32x4 sacc[4];
      __builtin_amdgcn_s_setprio(1);
      #pragma unroll
      for (int t = 0; t < 4; ++t) {
        const bf16x8 kf = *(const bf16x8*)(&sm.sK[cur][0] + (t * 16 + lr) * 64 + (((lg + 4) ^ xk) * 8));
        sacc[t] = __builtin_amdgcn_mfma_f32_16x16x32_bf16(kf, qf_k, fz, 0, 0, 0);
      }
      __builtin_amdgcn_s_setprio(0);
      softpv(sacc, 2);
    }
  };

  #pragma unroll 1
  for (int it = 0; it < 8; ++it) {
    const int kt0 = it * 4;
    const bool l7 = (it < 7);
    body(kt0 + 0, 0, 2, true, (kt0 == 0) ? 3 : 6, m0, &m2);
    body(kt0 + 1, 1, 3, true, 6, m1, &m3);
    body(kt0 + 2, 2, 0, l7, l7 ? 6 : 3, m2, &m0);
    body(kt0 + 3, 3, 1, l7, l7 ? 6 : 0, m3, &m1);
  }

  float linv[3][4];
  #pragma unroll
  for (int s = 0; s < 3; ++s)
    #pragma unroll
    for (int j = 0; j < 4; ++j)
      linv[s][j] = 1.0f / (3.0f * osum[s][j] + 1e-30f);

  #pragma unroll
  for (int ct = 0; ct < 4; ++ct) {
    float vj[4];
    #pragma unroll
    for (int j = 0; j < 4; ++j)
      vj[j] = oacc[0][ct][j] * linv[0][j]
            + oacc[1][ct][j] * linv[1][j]
            + oacc[2][ct][j] * linv[2][j];
    const u32 r01 = cvtpk(vj[0], vj[1]);
    const u32 r23 = cvtpk(vj[2], vj[3]);
    const u16 bvv[4] = {(u16)r01, (u16)(r01 >> 16), (u16)r23, (u16)(r23 >> 16)};
    #pragma unroll
    for (int j = 0; j < 4; ++j) {
      const int row = q0 + w * 16 + lg * 4 + j;
      const int col = h * 64 + ct * 16 + lr;
      aout[((size_t)b * 2048 + row) * 512 + col] = bvv[j];
    }
  }
}

// ---------- kernel 3: output projection, M64xN64 tiles ----------
__global__ __launch_bounds__(256) void out_gemm_kernel(
    const u16* __restrict__ A, const u16* __restrict__ Wo,
    const float* __restrict__ bias, float* __restrict__ out) {
  __shared__ u16 lA[64 * 64];
  __shared__ u16 lB[64 * 64];

  const int tid = threadIdx.x;
  const int w = tid >> 6, l = tid & 63;
  const int lr = l & 15, lg = l >> 4;

  const int wg = blockIdx.x;
  const int xcd = wg & 7;
  const int q = wg >> 3;
  const int mt = (xcd << 4) + (q >> 3);
  const int nt = q & 7;
  const int col0 = nt * 64;
  const int m0 = mt * 64;
  f32x4 acc[4] = {};
  const int ubase = tid & ~63;

  #pragma unroll 1
  for (int kt = 0; kt < 8; ++kt) {
    const int k0 = kt << 6;
    #pragma unroll
    for (int i = 0; i < 2; ++i) {
      const int ch = i * 256 + tid;
      const int row = ch >> 3, c8 = (ch & 7) << 3;
      gl_lds16(A + (size_t)(m0 + row) * 512 + k0 + c8, lA + (size_t)(i * 256 + ubase) * 8);
    }
    #pragma unroll
    for (int i = 0; i < 2; ++i) {
      const int ch = i * 256 + tid;
      const int row = ch >> 3, c8 = (ch & 7) << 3;
      gl_lds16(Wo + (size_t)(col0 + row) * 512 + k0 + c8, lB + (size_t)(i * 256 + ubase) * 8);
    }
    __syncthreads();
    bf16x8 af[4][2], bfr[2];
    #pragma unroll
    for (int mi = 0; mi < 4; ++mi) {
      af[mi][0] = *(const bf16x8*)(lA + (mi * 16 + lr) * 64 + lg * 8);
      af[mi][1] = *(const bf16x8*)(lA + (mi * 16 + lr) * 64 + 32 + lg * 8);
    }
    bfr[0] = *(const bf16x8*)(lB + (w * 16 + lr) * 64 + lg * 8);
    bfr[1] = *(const bf16x8*)(lB + (w * 16 + lr) * 64 + 32 + lg * 8);
    #pragma unroll
    for (int mi = 0; mi < 4; ++mi) {
      acc[mi] = __builtin_amdgcn_mfma_f32_16x16x32_bf16(af[mi][0], bfr[0], acc[mi], 0, 0, 0);
      acc[mi] = __builtin_amdgcn_mfma_f32_16x16x32_bf16(af[mi][1], bfr[1], acc[mi], 0, 0, 0);
    }
    __syncthreads();
  }

  const int c = col0 + w * 16 + lr;
  const float bv = bias[c];
  #pragma unroll
  for (int mi = 0; mi < 4; ++mi)
    #pragma unroll
    for (int j = 0; j < 4; ++j) {
      const int m = m0 + mi * 16 + lg * 4 + j;
      out[(size_t)m * 512 + c] = acc[mi][j] + bv;
    }
}

// ---------- launcher ----------
extern "C" void kernel_launch(void* const* d_in, const int* in_sizes, int n_in,
                              void* d_out, int out_size, void* d_ws, size_t ws_size,
                              hipStream_t stream) {
  const float* x    = (const float*)d_in[0];
  const float* Wa   = (const float*)d_in[1];
  const float* Wp   = (const float*)d_in[2];
  const float* Wk   = (const float*)d_in[3];
  const float* Wo   = (const float*)d_in[4];
  const float* bo   = (const float*)d_in[5];
  const int* mask   = (const int*)d_in[6];
  float* out = (float*)d_out;

  char* ws = (char*)d_ws;
  u16* Wab = (u16*)ws;                    //  3,145,728 B
  u16* Wpb = (u16*)(ws + 3145728);        //    786,432 B
  u16* Wkb = (u16*)(ws + 3932160);        //    786,432 B
  u16* Wob = (u16*)(ws + 4718592);        //    524,288 B
  u16* Qb  = (u16*)(ws + 5242880);        //  8,388,608 B  [B,H,N,64] bf16
  u16* Kb  = (u16*)(ws + 13631488);       //  8,388,608 B  [B,H,N,64] bf16
  u16* Vt  = (u16*)(ws + 22020096);       //  8,388,608 B  [B*H,64,2048] bf16 (sigma-perm)
  u64* Mb  = (u64*)(ws + 30408704);       //  2,097,152 B  bitmask
  u16* Ao  = (u16*)(ws + 32505856);       //  8,388,608 B  attn out [B,N,512] bf16
  u16* xb  = (u16*)(ws + 40894464);       // 67,108,864 B  x bf16 (optional)

  const bool use_xb = ws_size >= (size_t)40894464 + 67108864;
  const int xblocks = use_xb ? 8192 : 0;

  prep_kernel<<<xblocks + 2560 + 1024, 256, 0, stream>>>(
      x, xb, Wa, Wp, Wk, Wo, Wab, Wpb, Wkb, Wob, mask, (u64*)Mb, xblocks);
  if (use_xb) {
    qkv_gemm_kernel<<<1536, 256, 0, stream>>>(xb, Wab, Wpb, Wkb, Qb, Kb, Vt);
  } else {
    qkv_gemm_f32_kernel<<<768, 256, 0, stream>>>(x, Wab, Wpb, Wkb, Qb, Kb, Vt);
  }
  attn_kernel<<<512, 512, 0, stream>>>(Qb, Kb, Vt, (const u32*)Mb, Ao);
  out_gemm_kernel<<<1024, 256, 0, stream>>>(Ao, Wob, bo, out);
}

// Round 21
// 232.135 us; speedup vs baseline: 1.2489x; 1.0942x over previous
//
#include <hip/hip_runtime.h>
#include <hip/hip_bf16.h>

typedef __attribute__((ext_vector_type(8))) __bf16 bf16x8;
typedef __attribute__((ext_vector_type(4))) float f32x4;
typedef unsigned short u16;
typedef unsigned int u32;
typedef unsigned long long u64;

// ---------- helpers ----------
__device__ __forceinline__ u32 cvtpk(float lo, float hi) {  // {bf16(lo) | bf16(hi)<<16}
  u32 r;
  asm("v_cvt_pk_bf16_f32 %0, %1, %2" : "=v"(r) : "v"(lo), "v"(hi));
  return r;
}
__device__ __forceinline__ float rexp2(float x) {           // raw v_exp_f32 (2^x)
  float r;
  asm("v_exp_f32 %0, %1" : "=v"(r) : "v"(x));
  return r;
}
__device__ __forceinline__ void gl_lds16(const void* g, void* l) {
  __builtin_amdgcn_global_load_lds((const __attribute__((address_space(1))) void*)g,
                                   (__attribute__((address_space(3))) void*)l, 16, 0, 0);
}
__device__ __forceinline__ int sigma_inv(int n) {           // V key permutation (64-block)
  return ((n >> 5) << 5) | (((n & 15) >> 2) << 3) | ((n & 3) << 1) | ((n >> 4) & 1);
}

// ---------- kernel P: fused prep (maskbits | wcvt | xcvt) ----------
// Phase ORDER matters: maskbits (latency-bound, 8x-unrolled) dispatches FIRST so
// its dependent-load chains overlap the BW-bound xcvt stream instead of tailing.
__global__ __launch_bounds__(256) void prep_kernel(
    const float* __restrict__ x, u16* __restrict__ xb,
    const float* __restrict__ Wa, const float* __restrict__ Wp,
    const float* __restrict__ Wk, const float* __restrict__ Wo,
    u16* __restrict__ Wab, u16* __restrict__ Wpb,
    u16* __restrict__ Wkb, u16* __restrict__ Wob,
    const int* __restrict__ mask, u64* __restrict__ bits) {
  int bid = blockIdx.x;
  if (bid < 1024) {                          // ---- maskbits (8x unrolled ILP) ----
    const int lane = threadIdx.x & 63;
    const long long gw = (long long)bid * 4 + (threadIdx.x >> 6);  // 0..4095
    const long long nw = 4096;
    #pragma unroll 1
    for (int c = 0; c < 8; ++c) {
      const long long ib = gw + (long long)c * 8 * nw;
      int m[8];
      #pragma unroll
      for (int u = 0; u < 8; ++u)
        m[u] = mask[(ib + (long long)u * nw) * 64 + lane];
      #pragma unroll
      for (int u = 0; u < 8; ++u) {
        const u64 bal = __ballot(m[u] > 0);
        if (lane == 0) bits[ib + (long long)u * nw] = bal;
      }
    }
    return;
  }
  bid -= 1024;
  if (bid < 2560) {                          // ---- wcvt ----
    const float* s; u16* d; int base;
    if (bid < 1536)      { s = Wa; d = Wab; base = bid; }
    else if (bid < 1920) { s = Wp; d = Wpb; base = bid - 1536; }
    else if (bid < 2304) { s = Wk; d = Wkb; base = bid - 1920; }
    else                 { s = Wo; d = Wob; base = bid - 2304; }
    const int idx = (base * 256 + threadIdx.x) * 4;
    const float4 v = *(const float4*)(s + idx);
    *(uint2*)(d + idx) = make_uint2(cvtpk(v.x, v.y), cvtpk(v.z, v.w));
    return;
  }
  bid -= 2560;                               // ---- xcvt (4096 floats/block) ----
  const int base = bid * 4096 + threadIdx.x * 4;
  #pragma unroll
  for (int c = 0; c < 4; ++c) {
    const float4 a = *(const float4*)(x + base + c * 1024);
    *(uint2*)(xb + base + c * 1024) = make_uint2(cvtpk(a.x, a.y), cvtpk(a.z, a.w));
  }
}

// ---------- QKV Q/K store ----------
__device__ __forceinline__ void qk_store(
    float v0, float v1, float v2, float v3, int m_base, int c,
    int dhs, int seg, float fs,
    u16* __restrict__ Qb, u16* __restrict__ Kb) {
  const int which = c >> (3 + dhs);
  const float f = (which == 0) ? fs : 1.0f;
  const u32 r01 = cvtpk(v0 * f, v1 * f);
  const u32 r23 = cvtpk(v2 * f, v3 * f);
  const u16 bvv[4] = {(u16)r01, (u16)(r01 >> 16), (u16)r23, (u16)(r23 >> 16)};
  const int hd_mask = (8 << dhs) - 1;
  const int r = c & hd_mask;
  const int hh = r >> dhs;
  const int d = r & ((1 << dhs) - 1);
  #pragma unroll
  for (int j = 0; j < 4; ++j) {
    const int m = m_base + j;
    const int bb = m >> 11, n = m & 2047;
    const size_t bhn = (size_t)(bb * 8 + hh) * 2048 + n;
    const u16 bv = bvv[j];
    if (which == 0) Qb[bhn * 64 + seg + d] = bv;
    else            Kb[bhn * 64 + seg + d] = bv;
  }
}

// ---------- kernel 1a: QKV GEMM bf16, M64xN128 tiles ----------
// V-producing block types (nt in {4,5,8,11}) are PURE-V: epilogue does an LDS
// sigma-transpose and writes Vt[bh*64+d][n] directly.
__global__ __launch_bounds__(256) void qkv_gemm_kernel(
    const u16* __restrict__ xb, const u16* __restrict__ Wa,
    const u16* __restrict__ Wp, const u16* __restrict__ Wk,
    u16* __restrict__ Qb, u16* __restrict__ Kb, u16* __restrict__ Vt) {
  __shared__ u16 smem[64 * 64 + 128 * 64];   // 24 KB; V epilogue reuses as lt[128][72]
  u16* lA = smem;
  u16* lB = smem + 64 * 64;

  const int tid = threadIdx.x;
  const int w = tid >> 6, l = tid & 63;
  const int lr = l & 15, lg = l >> 4;

  const int wg = blockIdx.x;
  const int xcd = wg & 7;
  const int q = wg >> 3;
  const int mtl = q / 12, nt = q % 12;
  const int mt = (xcd << 4) + mtl;

  const u16* W; int xoff, Kd, col0, dhs, seg;
  if (nt < 6)      { W = Wa; xoff = 0;    Kd = 2048; col0 = nt * 128;       dhs = 5; seg = 0;  }
  else if (nt < 9) { W = Wp; xoff = 2048; Kd = 1024; col0 = (nt - 6) * 128; dhs = 4; seg = 32; }
  else             { W = Wk; xoff = 3072; Kd = 1024; col0 = (nt - 9) * 128; dhs = 4; seg = 48; }
  const float qscale = (dhs == 5) ? 0.031880107f : 0.045084220f;  // D^-0.5 * log2(e)
  const bool isV = (nt == 4) | (nt == 5) | (nt == 8) | (nt == 11);

  const int m0 = mt * 64;
  f32x4 acc[4][2] = {};
  const int ubase = tid & ~63;

  const int nk = Kd >> 6;
  #pragma unroll 1
  for (int kt = 0; kt < nk; ++kt) {
    const int k0 = kt << 6;
    #pragma unroll
    for (int i = 0; i < 2; ++i) {
      const int ch = i * 256 + tid;
      const int row = ch >> 3, c8 = (ch & 7) << 3;
      gl_lds16(xb + (size_t)(m0 + row) * 4096 + xoff + k0 + c8,
               lA + (size_t)(i * 256 + ubase) * 8);
    }
    #pragma unroll
    for (int i = 0; i < 4; ++i) {
      const int ch = i * 256 + tid;
      const int row = ch >> 3, c8 = (ch & 7) << 3;
      gl_lds16(W + (size_t)(col0 + row) * Kd + k0 + c8,
               lB + (size_t)(i * 256 + ubase) * 8);
    }
    __syncthreads();
    bf16x8 af[4][2], bfr[2][2];
    #pragma unroll
    for (int mi = 0; mi < 4; ++mi) {
      af[mi][0] = *(const bf16x8*)(lA + (mi * 16 + lr) * 64 + lg * 8);
      af[mi][1] = *(const bf16x8*)(lA + (mi * 16 + lr) * 64 + 32 + lg * 8);
    }
    #pragma unroll
    for (int ni = 0; ni < 2; ++ni) {
      bfr[ni][0] = *(const bf16x8*)(lB + (w * 32 + ni * 16 + lr) * 64 + lg * 8);
      bfr[ni][1] = *(const bf16x8*)(lB + (w * 32 + ni * 16 + lr) * 64 + 32 + lg * 8);
    }
    #pragma unroll
    for (int mi = 0; mi < 4; ++mi)
      #pragma unroll
      for (int ni = 0; ni < 2; ++ni) {
        acc[mi][ni] = __builtin_amdgcn_mfma_f32_16x16x32_bf16(af[mi][0], bfr[ni][0], acc[mi][ni], 0, 0, 0);
        acc[mi][ni] = __builtin_amdgcn_mfma_f32_16x16x32_bf16(af[mi][1], bfr[ni][1], acc[mi][ni], 0, 0, 0);
      }
    __syncthreads();
  }

  if (!isV) {
    #pragma unroll
    for (int mi = 0; mi < 4; ++mi)
      #pragma unroll
      for (int ni = 0; ni < 2; ++ni)
        qk_store(acc[mi][ni][0], acc[mi][ni][1], acc[mi][ni][2], acc[mi][ni][3],
                 m0 + mi * 16 + lg * 4, col0 + w * 32 + ni * 16 + lr,
                 dhs, seg, qscale, Qb, Kb);
  } else {
    // sigma-transpose via LDS: lt[c 0..127][pos 0..63] stride 72
    #pragma unroll
    for (int mi = 0; mi < 4; ++mi)
      #pragma unroll
      for (int ni = 0; ni < 2; ++ni) {
        const u32 r01 = cvtpk(acc[mi][ni][0], acc[mi][ni][1]);
        const u32 r23 = cvtpk(acc[mi][ni][2], acc[mi][ni][3]);
        const u16 bvv[4] = {(u16)r01, (u16)(r01 >> 16), (u16)r23, (u16)(r23 >> 16)};
        const int cl = w * 32 + ni * 16 + lr;
        #pragma unroll
        for (int j = 0; j < 4; ++j) {
          const int n = mi * 16 + lg * 4 + j;
          smem[cl * 72 + sigma_inv(n)] = bvv[j];
        }
      }
    __syncthreads();
    const int c = tid >> 1, half = (tid & 1) << 5;
    const int hd_mask = (8 << dhs) - 1;
    const int r = (col0 + c) & hd_mask;
    const int hh = r >> dhs, d = r & ((1 << dhs) - 1);
    const int bb = m0 >> 11, n0v = m0 & 2047;
    u16* dst = Vt + ((size_t)(bb * 8 + hh) * 64 + seg + d) * 2048 + n0v + half;
    const u16* srcl = smem + c * 72 + half;
    #pragma unroll
    for (int e = 0; e < 4; ++e)
      *(uint4*)(dst + e * 8) = *(const uint4*)(srcl + e * 8);
  }
}

// ---------- kernel 1b: fallback, x fp32 reg-staged (writes Vt scattered) ----------
__global__ __launch_bounds__(256) void qkv_gemm_f32_kernel(
    const float* __restrict__ x, const u16* __restrict__ Wa,
    const u16* __restrict__ Wp, const u16* __restrict__ Wk,
    u16* __restrict__ Qb, u16* __restrict__ Kb, u16* __restrict__ Vt) {
  __shared__ u16 lA[128 * 64];
  __shared__ u16 lB[128 * 64];

  const int tid = threadIdx.x;
  const int w = tid >> 6, l = tid & 63;
  const int lr = l & 15, lg = l >> 4;
  const int wr = w >> 1, wc = w & 1;

  const int wg = blockIdx.x;
  const int xcd = wg & 7;
  const int q = wg >> 3;
  const int mtl = q / 12, nt = q % 12;
  const int mt = (xcd << 3) + mtl;

  const u16* W; int xoff, Kd, col0, dhs, seg;
  if (nt < 6)      { W = Wa; xoff = 0;    Kd = 2048; col0 = nt * 128;       dhs = 5; seg = 0;  }
  else if (nt < 9) { W = Wp; xoff = 2048; Kd = 1024; col0 = (nt - 6) * 128; dhs = 4; seg = 32; }
  else             { W = Wk; xoff = 3072; Kd = 1024; col0 = (nt - 9) * 128; dhs = 4; seg = 48; }
  const float qscale = (dhs == 5) ? 0.031880107f : 0.045084220f;

  const int m0 = mt * 128;
  f32x4 acc[4][4] = {};
  const int ubase = tid & ~63;

  const int nk = Kd >> 6;
  #pragma unroll 1
  for (int kt = 0; kt < nk; ++kt) {
    const int k0 = kt << 6;
    #pragma unroll
    for (int i = 0; i < 4; ++i) {
      const int ch = i * 256 + tid;
      const int row = ch >> 3, c8 = (ch & 7) << 3;
      const float* src = x + (size_t)(m0 + row) * 4096 + xoff + k0 + c8;
      const float4 a0 = *(const float4*)(src);
      const float4 a1 = *(const float4*)(src + 4);
      uint4 t;
      t.x = cvtpk(a0.x, a0.y); t.y = cvtpk(a0.z, a0.w);
      t.z = cvtpk(a1.x, a1.y); t.w = cvtpk(a1.z, a1.w);
      *(uint4*)(lA + (size_t)row * 64 + c8) = t;
    }
    #pragma unroll
    for (int i = 0; i < 4; ++i) {
      const int ch = i * 256 + tid;
      const int row = ch >> 3, c8 = (ch & 7) << 3;
      gl_lds16(W + (size_t)(col0 + row) * Kd + k0 + c8,
               lB + (size_t)(i * 256 + ubase) * 8);
    }
    __syncthreads();
    bf16x8 af[4][2], bfr[4][2];
    #pragma unroll
    for (int mi = 0; mi < 4; ++mi) {
      af[mi][0] = *(const bf16x8*)(lA + (wr * 64 + mi * 16 + lr) * 64 + lg * 8);
      af[mi][1] = *(const bf16x8*)(lA + (wr * 64 + mi * 16 + lr) * 64 + 32 + lg * 8);
    }
    #pragma unroll
    for (int ni = 0; ni < 4; ++ni) {
      bfr[ni][0] = *(const bf16x8*)(lB + (wc * 64 + ni * 16 + lr) * 64 + lg * 8);
      bfr[ni][1] = *(const bf16x8*)(lB + (wc * 64 + ni * 16 + lr) * 64 + 32 + lg * 8);
    }
    #pragma unroll
    for (int mi = 0; mi < 4; ++mi)
      #pragma unroll
      for (int ni = 0; ni < 4; ++ni) {
        acc[mi][ni] = __builtin_amdgcn_mfma_f32_16x16x32_bf16(af[mi][0], bfr[ni][0], acc[mi][ni], 0, 0, 0);
        acc[mi][ni] = __builtin_amdgcn_mfma_f32_16x16x32_bf16(af[mi][1], bfr[ni][1], acc[mi][ni], 0, 0, 0);
      }
    __syncthreads();
  }
  #pragma unroll
  for (int mi = 0; mi < 4; ++mi)
    #pragma unroll
    for (int ni = 0; ni < 4; ++ni) {
      const int c = col0 + wc * 64 + ni * 16 + lr;
      const int which = c >> (3 + dhs);
      const float f = (which == 0) ? qscale : 1.0f;
      const u32 r01 = cvtpk(acc[mi][ni][0] * f, acc[mi][ni][1] * f);
      const u32 r23 = cvtpk(acc[mi][ni][2] * f, acc[mi][ni][3] * f);
      const u16 bvv[4] = {(u16)r01, (u16)(r01 >> 16), (u16)r23, (u16)(r23 >> 16)};
      const int hd_mask = (8 << dhs) - 1;
      const int r = c & hd_mask;
      const int hh = r >> dhs;
      const int d = r & ((1 << dhs) - 1);
      #pragma unroll
      for (int j = 0; j < 4; ++j) {
        const int m = m0 + wr * 64 + mi * 16 + lg * 4 + j;
        const int bb = m >> 11, n = m & 2047;
        const size_t bhn = (size_t)(bb * 8 + hh) * 2048 + n;
        const u16 bv = bvv[j];
        if (which == 0)      Qb[bhn * 64 + seg + d] = bv;
        else if (which == 1) Kb[bhn * 64 + seg + d] = bv;
        else Vt[((size_t)(bb * 8 + hh) * 64 + seg + d) * 2048 + (n & ~63) + sigma_inv(n & 63)] = bv;
      }
    }
}

// ---------- kernel 2: fused 3-branch flash attention ----------
// QBLK=128 (512 thr). 4-buffer LDS (64 KB), stage-ahead-2, ONE barrier/tile.
// vmcnt(6) steady state = {mask,K,V} x 2 newest bodies in flight.
__global__ __launch_bounds__(512) void attn_kernel(
    const u16* __restrict__ Qb, const u16* __restrict__ Kb,
    const u16* __restrict__ Vt, const u32* __restrict__ mbits,
    u16* __restrict__ aout) {
  struct SMem {
    u16 sK[4][64 * 64];   // 4 x 8192 B
    u16 sV[4][64 * 64];   // 4 x 8192 B
  };
  __shared__ SMem sm;     // 65536 B

  const int tid = threadIdx.x;
  const int w = tid >> 6, l = tid & 63;
  const int lr = l & 15, lg = l >> 4;
  const int wg = blockIdx.x;            // 0..511
  const int xcd = wg & 7, rr0 = wg >> 3;
  const int bh = (xcd << 2) + (rr0 >> 4);   // each XCD: 4 bh x 16 qt
  const int qt = rr0 & 15;
  const int b = bh >> 3, h = bh & 7;
  const int q0 = qt << 7;               // 128 q-rows per block
  const size_t bhN = (size_t)bh * 2048;
  const int ubase = tid & ~63;

  const u16* qrow = Qb + (bhN + q0 + w * 16 + lr) * 64;
  const bf16x8 qf_a  = *(const bf16x8*)(qrow + lg * 8);
  const bf16x8 qf_pk = *(const bf16x8*)(qrow + 32 + lg * 8);
  bf16x8 zero8 = {};
  const bf16x8 qf_p = (lg < 2) ? qf_pk : zero8;
  const bf16x8 qf_k = (lg < 2) ? zero8 : qf_pk;

  const u32* mptr = mbits + ((size_t)b * 2048 + q0 + w * 16 + lr) * 64;

  const int sr = tid >> 3, swd = tid & 7;
  const u16* kp = Kb + (bhN + sr) * 64 + (swd ^ (sr & 7)) * 8;          // + kt*4096
  const u16* vp = Vt + ((size_t)bh * 64 + sr) * 2048 + (swd ^ (sr & 7)) * 8;  // + kt*64
  u16* dK[4] = { &sm.sK[0][0] + ubase * 8, &sm.sK[1][0] + ubase * 8,
                 &sm.sK[2][0] + ubase * 8, &sm.sK[3][0] + ubase * 8 };
  u16* dV[4] = { &sm.sV[0][0] + ubase * 8, &sm.sV[1][0] + ubase * 8,
                 &sm.sV[2][0] + ubase * 8, &sm.sV[3][0] + ubase * 8 };

  // prologue: stage tiles 0,1 + masks 0,1
  gl_lds16(kp, dK[0]);               gl_lds16(vp, dV[0]);
  gl_lds16(kp + 4096, dK[1]);        gl_lds16(vp + 64, dV[1]);
  uint2 m0 = *(const uint2*)(mptr);
  uint2 m1 = *(const uint2*)(mptr + 2);
  uint2 m2, m3;

  bf16x8 vones;
  #pragma unroll
  for (int e = 0; e < 8; ++e) vones[e] = __builtin_bit_cast(__bf16, (u16)0x3F80);

  f32x4 oacc[3][4] = {};
  f32x4 osum[3] = {};
  const int c4 = (lg << 2);
  const int xk = lr & 7;

  auto body = [&](int kt, int cur, int sb, bool st2, int wc, uint2 mkv, uint2* mknext) {
    if (st2) {
      *mknext = *(const uint2*)(mptr + ((kt + 2) << 1));   // mask(kt+2)
      gl_lds16(kp + (size_t)(kt + 2) * 4096, dK[sb]);
      gl_lds16(vp + (size_t)(kt + 2) * 64, dV[sb]);
    }
    if (wc == 6)      asm volatile("s_waitcnt vmcnt(6)" ::: "memory");
    else if (wc == 3) asm volatile("s_waitcnt vmcnt(3)" ::: "memory");
    else              asm volatile("s_waitcnt vmcnt(0)" ::: "memory");
    __builtin_amdgcn_sched_barrier(0);
    __builtin_amdgcn_s_barrier();   // single barrier per tile

    u32 msk[4][2];
    #pragma unroll
    for (int j = 0; j < 4; ++j) {
      const int c = c4 + j;
      const u32 u0 = (mkv.x >> c) & 0x00010001u;
      const u32 u1 = (mkv.y >> c) & 0x00010001u;
      msk[j][0] = (u0 << 16) - u0;
      msk[j][1] = (u1 << 16) - u1;
    }

    bf16x8 vb[4][2];
    #pragma unroll
    for (int ct = 0; ct < 4; ++ct) {
      const u16* vrow = &sm.sV[cur][0] + (ct * 16 + lr) * 64;
      vb[ct][0] = *(const bf16x8*)(vrow + (lg ^ xk) * 8);
      vb[ct][1] = *(const bf16x8*)(vrow + ((lg + 4) ^ xk) * 8);
    }

    const f32x4 fz = {0.f, 0.f, 0.f, 0.f};
    auto softpv = [&](f32x4 (&sacc)[4], int s) {
      uint4 pw0, pw1;
      u32* w0 = (u32*)&pw0; u32* w1 = (u32*)&pw1;
      #pragma unroll
      for (int j = 0; j < 4; ++j) {
        w0[j] = cvtpk(rexp2(sacc[0][j]), rexp2(sacc[1][j])) & msk[j][0];
        w1[j] = cvtpk(rexp2(sacc[2][j]), rexp2(sacc[3][j])) & msk[j][1];
      }
      const bf16x8 pa0 = __builtin_bit_cast(bf16x8, pw0);
      const bf16x8 pa1 = __builtin_bit_cast(bf16x8, pw1);
      __builtin_amdgcn_s_setprio(1);
      #pragma unroll
      for (int ct = 0; ct < 4; ++ct) {
        oacc[s][ct] = __builtin_amdgcn_mfma_f32_16x16x32_bf16(pa0, vb[ct][0], oacc[s][ct], 0, 0, 0);
        oacc[s][ct] = __builtin_amdgcn_mfma_f32_16x16x32_bf16(pa1, vb[ct][1], oacc[s][ct], 0, 0, 0);
      }
      osum[s] = __builtin_amdgcn_mfma_f32_16x16x32_bf16(pa0, vones, osum[s], 0, 0, 0);
      osum[s] = __builtin_amdgcn_mfma_f32_16x16x32_bf16(pa1, vones, osum[s], 0, 0, 0);
      __builtin_amdgcn_s_setprio(0);
    };

    {  // segment a
      f32x4 sacc[4];
      __builtin_amdgcn_s_setprio(1);
      #pragma unroll
      for (int t = 0; t < 4; ++t) {
        const bf16x8 kf = *(const bf16x8*)(&sm.sK[cur][0] + (t * 16 + lr) * 64 + ((lg ^ xk) * 8));
        sacc[t] = __builtin_amdgcn_mfma_f32_16x16x32_bf16(kf, qf_a, fz, 0, 0, 0);
      }
      __builtin_amdgcn_s_setprio(0);
      softpv(sacc, 0);
    }
    {  // segment p
      f32x4 sacc[4];
      __builtin_amdgcn_s_setprio(1);
      #pragma unroll
      for (int t = 0; t < 4; ++t) {
        const bf16x8 kf = *(const bf16x8*)(&sm.sK[cur][0] + (t * 16 + lr) * 64 + (((lg + 4) ^ xk) * 8));
        sacc[t] = __builtin_amdgcn_mfma_f32_16x16x32_bf16(kf, qf_p, fz, 0, 0, 0);
      }
      __builtin_amdgcn_s_setprio(0);
      softpv(sacc, 1);
    }
    {  // segment k
      f32x4 sacc[4];
      __builtin_amdgcn_s_setprio(1);
      #pragma unroll
      for (int t = 0; t < 4; ++t) {
        const bf16x8 kf = *(const bf16x8*)(&sm.sK[cur][0] + (t * 16 + lr) * 64 + (((lg + 4) ^ xk) * 8));
        sacc[t] = __builtin_amdgcn_mfma_f32_16x16x32_bf16(kf, qf_k, fz, 0, 0, 0);
      }
      __builtin_amdgcn_s_setprio(0);
      softpv(sacc, 2);
    }
  };

  #pragma unroll 1
  for (int it = 0; it < 8; ++it) {
    const int kt0 = it * 4;
    const bool l7 = (it < 7);
    body(kt0 + 0, 0, 2, true, (kt0 == 0) ? 3 : 6, m0, &m2);
    body(kt0 + 1, 1, 3, true, 6, m1, &m3);
    body(kt0 + 2, 2, 0, l7, l7 ? 6 : 3, m2, &m0);
    body(kt0 + 3, 3, 1, l7, l7 ? 6 : 0, m3, &m1);
  }

  float linv[3][4];
  #pragma unroll
  for (int s = 0; s < 3; ++s)
    #pragma unroll
    for (int j = 0; j < 4; ++j)
      linv[s][j] = 1.0f / (3.0f * osum[s][j] + 1e-30f);

  #pragma unroll
  for (int ct = 0; ct < 4; ++ct) {
    float vj[4];
    #pragma unroll
    for (int j = 0; j < 4; ++j)
      vj[j] = oacc[0][ct][j] * linv[0][j]
            + oacc[1][ct][j] * linv[1][j]
            + oacc[2][ct][j] * linv[2][j];
    const u32 r01 = cvtpk(vj[0], vj[1]);
    const u32 r23 = cvtpk(vj[2], vj[3]);
    const u16 bvv[4] = {(u16)r01, (u16)(r01 >> 16), (u16)r23, (u16)(r23 >> 16)};
    #pragma unroll
    for (int j = 0; j < 4; ++j) {
      const int row = q0 + w * 16 + lg * 4 + j;
      const int col = h * 64 + ct * 16 + lr;
      aout[((size_t)b * 2048 + row) * 512 + col] = bvv[j];
    }
  }
}

// ---------- kernel 3: output projection, M64xN64 tiles ----------
__global__ __launch_bounds__(256) void out_gemm_kernel(
    const u16* __restrict__ A, const u16* __restrict__ Wo,
    const float* __restrict__ bias, float* __restrict__ out) {
  __shared__ u16 lA[64 * 64];
  __shared__ u16 lB[64 * 64];

  const int tid = threadIdx.x;
  const int w = tid >> 6, l = tid & 63;
  const int lr = l & 15, lg = l >> 4;

  const int wg = blockIdx.x;
  const int xcd = wg & 7;
  const int q = wg >> 3;
  const int mt = (xcd << 4) + (q >> 3);
  const int nt = q & 7;
  const int col0 = nt * 64;
  const int m0 = mt * 64;
  f32x4 acc[4] = {};
  const int ubase = tid & ~63;

  #pragma unroll 1
  for (int kt = 0; kt < 8; ++kt) {
    const int k0 = kt << 6;
    #pragma unroll
    for (int i = 0; i < 2; ++i) {
      const int ch = i * 256 + tid;
      const int row = ch >> 3, c8 = (ch & 7) << 3;
      gl_lds16(A + (size_t)(m0 + row) * 512 + k0 + c8, lA + (size_t)(i * 256 + ubase) * 8);
    }
    #pragma unroll
    for (int i = 0; i < 2; ++i) {
      const int ch = i * 256 + tid;
      const int row = ch >> 3, c8 = (ch & 7) << 3;
      gl_lds16(Wo + (size_t)(col0 + row) * 512 + k0 + c8, lB + (size_t)(i * 256 + ubase) * 8);
    }
    __syncthreads();
    bf16x8 af[4][2], bfr[2];
    #pragma unroll
    for (int mi = 0; mi < 4; ++mi) {
      af[mi][0] = *(const bf16x8*)(lA + (mi * 16 + lr) * 64 + lg * 8);
      af[mi][1] = *(const bf16x8*)(lA + (mi * 16 + lr) * 64 + 32 + lg * 8);
    }
    bfr[0] = *(const bf16x8*)(lB + (w * 16 + lr) * 64 + lg * 8);
    bfr[1] = *(const bf16x8*)(lB + (w * 16 + lr) * 64 + 32 + lg * 8);
    #pragma unroll
    for (int mi = 0; mi < 4; ++mi) {
      acc[mi] = __builtin_amdgcn_mfma_f32_16x16x32_bf16(af[mi][0], bfr[0], acc[mi], 0, 0, 0);
      acc[mi] = __builtin_amdgcn_mfma_f32_16x16x32_bf16(af[mi][1], bfr[1], acc[mi], 0, 0, 0);
    }
    __syncthreads();
  }

  const int c = col0 + w * 16 + lr;
  const float bv = bias[c];
  #pragma unroll
  for (int mi = 0; mi < 4; ++mi)
    #pragma unroll
    for (int j = 0; j < 4; ++j) {
      const int m = m0 + mi * 16 + lg * 4 + j;
      out[(size_t)m * 512 + c] = acc[mi][j] + bv;
    }
}

// ---------- launcher ----------
extern "C" void kernel_launch(void* const* d_in, const int* in_sizes, int n_in,
                              void* d_out, int out_size, void* d_ws, size_t ws_size,
                              hipStream_t stream) {
  const float* x    = (const float*)d_in[0];
  const float* Wa   = (const float*)d_in[1];
  const float* Wp   = (const float*)d_in[2];
  const float* Wk   = (const float*)d_in[3];
  const float* Wo   = (const float*)d_in[4];
  const float* bo   = (const float*)d_in[5];
  const int* mask   = (const int*)d_in[6];
  float* out = (float*)d_out;

  char* ws = (char*)d_ws;
  u16* Wab = (u16*)ws;                    //  3,145,728 B
  u16* Wpb = (u16*)(ws + 3145728);        //    786,432 B
  u16* Wkb = (u16*)(ws + 3932160);        //    786,432 B
  u16* Wob = (u16*)(ws + 4718592);        //    524,288 B
  u16* Qb  = (u16*)(ws + 5242880);        //  8,388,608 B  [B,H,N,64] bf16
  u16* Kb  = (u16*)(ws + 13631488);       //  8,388,608 B  [B,H,N,64] bf16
  u16* Vt  = (u16*)(ws + 22020096);       //  8,388,608 B  [B*H,64,2048] bf16 (sigma-perm)
  u64* Mb  = (u64*)(ws + 30408704);       //  2,097,152 B  bitmask
  u16* Ao  = (u16*)(ws + 32505856);       //  8,388,608 B  attn out [B,N,512] bf16
  u16* xb  = (u16*)(ws + 40894464);       // 67,108,864 B  x bf16 (optional)

  const bool use_xb = ws_size >= (size_t)40894464 + 67108864;
  const int xblocks = use_xb ? 8192 : 0;

  prep_kernel<<<1024 + 2560 + xblocks, 256, 0, stream>>>(
      x, xb, Wa, Wp, Wk, Wo, Wab, Wpb, Wkb, Wob, mask, (u64*)Mb);
  if (use_xb) {
    qkv_gemm_kernel<<<1536, 256, 0, stream>>>(xb, Wab, Wpb, Wkb, Qb, Kb, Vt);
  } else {
    qkv_gemm_f32_kernel<<<768, 256, 0, stream>>>(x, Wab, Wpb, Wkb, Qb, Kb, Vt);
  }
  attn_kernel<<<512, 512, 0, stream>>>(Qb, Kb, Vt, (const u32*)Mb, Ao);
  out_gemm_kernel<<<1024, 256, 0, stream>>>(Ao, Wob, bo, out);
}